// Round 1
// baseline (431.533 us; speedup 1.0000x reference)
//
#include <hip/hip_runtime.h>
#include <cstdint>
#include <cstddef>

#define EPSV 1e-5f
#define NB 1024
#define NNODE 65536
#define NEDGE 1048576
#define EPG 1024
#define CNTF 65536.0f

// ---------------------------------------------------------------------------
// Stage 1: EdgeConv. One block per graph. h = relu([xi, xj-xi]@w1 + b1) (4-dim)
// is segment-summed in LDS (plus degree count), then expanded through w2 once
// per node: out0[n][c] = agg[n]@w2[:,c] + deg[n]*b2[c]. Also accumulates
// per-channel sum/sumsq for BN1 (global atomics, 128 per block).
// out0 layout: [node][channel] = [b*64+l][c]
// ---------------------------------------------------------------------------
__global__ __launch_bounds__(256) void k_edge(
    const float* __restrict__ x, const int* __restrict__ ei,
    const float* __restrict__ w1, const float* __restrict__ b1,
    const float* __restrict__ w2, const float* __restrict__ b2,
    float* __restrict__ out0, float* __restrict__ stats1)
{
  __shared__ float xs[64];
  __shared__ float agg[64][8];   // cols 0..3 = hidden sums, col 4 = degree
  __shared__ float w1s[8], b1s[4];
  __shared__ float w2s[256], b2s[64];
  __shared__ float rs[4][64], rss[4][64];
  const int tid = threadIdx.x;
  const int b = blockIdx.x;

  if (tid < 8) w1s[tid] = w1[tid];
  if (tid < 4) b1s[tid] = b1[tid];
  if (tid < 64) { xs[tid] = x[(b << 6) + tid]; b2s[tid] = b2[tid]; }
  w2s[tid] = w2[tid];
  for (int i = tid; i < 512; i += 256) ((float*)agg)[i] = 0.f;
  __syncthreads();

  const int e0 = b * EPG;
  for (int i = tid; i < EPG; i += 256) {
    const int e = e0 + i;
    const int sl = ei[e] & 63;          // src (local)
    const int dl = ei[NEDGE + e] & 63;  // dst (local)
    const float xi = xs[dl];
    const float dx = xs[sl] - xi;
#pragma unroll
    for (int j = 0; j < 4; ++j) {
      float h = fmaxf(fmaf(xi, w1s[j], fmaf(dx, w1s[4 + j], b1s[j])), 0.f);
      atomicAdd(&agg[dl][j], h);
    }
    atomicAdd(&agg[dl][4], 1.0f);
  }
  __syncthreads();

  const int c = tid & 63, q = tid >> 6;
  const float wc0 = w2s[c], wc1 = w2s[64 + c], wc2 = w2s[128 + c], wc3 = w2s[192 + c];
  const float b2c = b2s[c];
  float s = 0.f, ss = 0.f;
  for (int n = q; n < 64; n += 4) {
    float v = agg[n][0] * wc0 + agg[n][1] * wc1 + agg[n][2] * wc2 +
              agg[n][3] * wc3 + agg[n][4] * b2c;
    out0[(size_t)(((b << 6) + n) << 6) + c] = v;
    s += v; ss += v * v;
  }
  rs[q][c] = s; rss[q][c] = ss;
  __syncthreads();
  if (tid < 64) {
    atomicAdd(&stats1[tid], rs[0][tid] + rs[1][tid] + rs[2][tid] + rs[3][tid]);
    atomicAdd(&stats1[64 + tid], rss[0][tid] + rss[1][tid] + rss[2][tid] + rss[3][tid]);
  }
}

// ---------------------------------------------------------------------------
// Stage 2/3: BN(stats_in)+ReLU on input, Conv1d(64,64,3,pad=1), write pre-BN
// output + accumulate per-channel BN stats. One block per graph.
// transpose_in=1: in layout [b][l][c] (stage-1 output); =0: [b][c][l].
// out layout: [b][o][l]. Weights staged in LDS in two halves (<64KB static).
// Thread tile: 4 (o) x 4 (l); 256 threads = 16 tl-groups x 16 to-groups.
// ---------------------------------------------------------------------------
__global__ __launch_bounds__(256) void k_conv(
    const float* __restrict__ in, const int transpose_in,
    const float* __restrict__ stats_in,
    const float* __restrict__ gamma, const float* __restrict__ beta,
    const float* __restrict__ cw, const float* __restrict__ cb,
    float* __restrict__ out, float* __restrict__ stats_out)
{
  __shared__ float Wt[96][66];   // [ck-local][o], ck = c*3+k, half of 192 rows
  __shared__ float Y[64][66];    // [c][l+1], cols 0 and 65 are zero pads
  __shared__ float aco[64], bco[64], cbs[64];
  __shared__ float ldsS[64], ldsSS[64];
  const int tid = threadIdx.x;
  const int b = blockIdx.x;

  if (tid < 64) {
    const float sm = stats_in[tid], sq = stats_in[64 + tid];
    const float mean = sm * (1.0f / CNTF);
    const float var = sq * (1.0f / CNTF) - mean * mean;
    const float a = gamma[tid] * rsqrtf(var + EPSV);
    aco[tid] = a;
    bco[tid] = beta[tid] - mean * a;
    cbs[tid] = cb[tid];
    Y[tid][0] = 0.f;
    Y[tid][65] = 0.f;
  }
  __syncthreads();

  const size_t base = (size_t)b << 12;
  if (transpose_in) {
    for (int idx = tid; idx < 4096; idx += 256) {
      const int l = idx >> 6, c = idx & 63;
      const float v = in[base + idx];
      Y[c][l + 1] = fmaxf(fmaf(aco[c], v, bco[c]), 0.f);
    }
  } else {
    for (int idx = tid; idx < 4096; idx += 256) {
      const int c = idx >> 6, l = idx & 63;
      const float v = in[base + idx];
      Y[c][l + 1] = fmaxf(fmaf(aco[c], v, bco[c]), 0.f);
    }
  }
  // W half 0: ck rows 0..95 (c 0..31)
  for (int idx = tid; idx < 6144; idx += 256) {
    const int o = idx / 96, r = idx - o * 96;
    Wt[r][o] = cw[o * 192 + r];
  }
  __syncthreads();

  const int tl = tid & 15, to = tid >> 4;
  const int lbase = tl << 2, obase = to << 2;
  float acc[4][4];
#pragma unroll
  for (int i = 0; i < 4; ++i) {
    const float cbv = cbs[obase + i];
#pragma unroll
    for (int jj = 0; jj < 4; ++jj) acc[i][jj] = cbv;
  }

#pragma unroll 1
  for (int half = 0; half < 2; ++half) {
    if (half == 1) {
      __syncthreads();
      for (int idx = tid; idx < 6144; idx += 256) {
        const int o = idx / 96, r = idx - o * 96;
        Wt[r][o] = cw[o * 192 + 96 + r];
      }
      __syncthreads();
    }
    const int cbase = half << 5;
    for (int cc = 0; cc < 32; ++cc) {
      const int cg = cbase + cc;
      const float2 y01 = *(const float2*)&Y[cg][lbase];
      const float2 y23 = *(const float2*)&Y[cg][lbase + 2];
      const float2 y45 = *(const float2*)&Y[cg][lbase + 4];
      const float yv[6] = {y01.x, y01.y, y23.x, y23.y, y45.x, y45.y};
#pragma unroll
      for (int k = 0; k < 3; ++k) {
        const float2 wa = *(const float2*)&Wt[cc * 3 + k][obase];
        const float2 wb = *(const float2*)&Wt[cc * 3 + k][obase + 2];
#pragma unroll
        for (int jj = 0; jj < 4; ++jj) {
          const float yy = yv[jj + k];
          acc[0][jj] = fmaf(wa.x, yy, acc[0][jj]);
          acc[1][jj] = fmaf(wa.y, yy, acc[1][jj]);
          acc[2][jj] = fmaf(wb.x, yy, acc[2][jj]);
          acc[3][jj] = fmaf(wb.y, yy, acc[3][jj]);
        }
      }
    }
  }

  // store + per-channel stats (reduce over tl via 16-lane shuffle groups)
#pragma unroll
  for (int i = 0; i < 4; ++i) {
    const int o = obase + i;
    float4 v4 = make_float4(acc[i][0], acc[i][1], acc[i][2], acc[i][3]);
    *(float4*)&out[base + (size_t)(o << 6) + lbase] = v4;
    float s = acc[i][0] + acc[i][1] + acc[i][2] + acc[i][3];
    float ssq = acc[i][0] * acc[i][0] + acc[i][1] * acc[i][1] +
                acc[i][2] * acc[i][2] + acc[i][3] * acc[i][3];
#pragma unroll
    for (int off = 1; off < 16; off <<= 1) {
      s += __shfl_xor(s, off);
      ssq += __shfl_xor(ssq, off);
    }
    if (tl == 0) { ldsS[o] = s; ldsSS[o] = ssq; }
  }
  __syncthreads();
  if (tid < 64) {
    atomicAdd(&stats_out[tid], ldsS[tid]);
    atomicAdd(&stats_out[64 + tid], ldsSS[tid]);
  }
}

// ---------------------------------------------------------------------------
// Stage 4: BN3+ReLU, then 4096->256->256->256->16 MLP + log_softmax.
// 8 graphs per block, 512 threads: thread = (col j in 0..255, graph-half gh).
// Y chunk [512 k][8 g] in LDS (float4 broadcast); h layers stored transposed
// [k][g] so the next layer reads float4 broadcasts too.
// ---------------------------------------------------------------------------
__global__ __launch_bounds__(512) void k_mlp(
    const float* __restrict__ z3, const float* __restrict__ stats3,
    const float* __restrict__ g3, const float* __restrict__ be3,
    const float* __restrict__ wm1, const float* __restrict__ bm1,
    const float* __restrict__ wm2, const float* __restrict__ bm2,
    const float* __restrict__ wm3, const float* __restrict__ bm3,
    const float* __restrict__ wp, const float* __restrict__ bp,
    float* __restrict__ out)
{
  __shared__ float a3[64], b3[64];
  __shared__ float Ych[512][8];
  __shared__ float hA[256][8];
  __shared__ float hB[256][8];
  const int tid = threadIdx.x;
  const int b0 = blockIdx.x << 3;
  const int j = tid & 255, gh = tid >> 8;  // gh in {0,1} -> graphs gh*4..gh*4+3

  if (tid < 64) {
    const float sm = stats3[tid], sq = stats3[64 + tid];
    const float mean = sm * (1.0f / CNTF);
    const float var = sq * (1.0f / CNTF) - mean * mean;
    const float a = g3[tid] * rsqrtf(var + EPSV);
    a3[tid] = a;
    b3[tid] = be3[tid] - mean * a;
  }
  __syncthreads();

  float acc[4] = {0.f, 0.f, 0.f, 0.f};
  for (int kc = 0; kc < 4096; kc += 512) {
    for (int idx = tid; idx < 4096; idx += 512) {
      const int g = idx >> 9, kk = idx & 511;
      const int k = kc + kk, c = k >> 6;
      const float v = z3[((size_t)(b0 + g) << 12) + k];
      Ych[kk][g] = fmaxf(fmaf(a3[c], v, b3[c]), 0.f);
    }
    __syncthreads();
    for (int kk = 0; kk < 512; ++kk) {
      const float4 y = *(const float4*)&Ych[kk][gh << 2];
      const float w = wm1[((size_t)(kc + kk) << 8) + j];
      acc[0] = fmaf(y.x, w, acc[0]);
      acc[1] = fmaf(y.y, w, acc[1]);
      acc[2] = fmaf(y.z, w, acc[2]);
      acc[3] = fmaf(y.w, w, acc[3]);
    }
    __syncthreads();
  }
  {
    const float bm = bm1[j];
    float4 h;
    h.x = fmaxf(acc[0] + bm, 0.f);
    h.y = fmaxf(acc[1] + bm, 0.f);
    h.z = fmaxf(acc[2] + bm, 0.f);
    h.w = fmaxf(acc[3] + bm, 0.f);
    *(float4*)&hA[j][gh << 2] = h;
  }
  __syncthreads();

  float a2[4] = {0.f, 0.f, 0.f, 0.f};
  for (int k = 0; k < 256; ++k) {
    const float4 y = *(const float4*)&hA[k][gh << 2];
    const float w = wm2[(k << 8) + j];
    a2[0] = fmaf(y.x, w, a2[0]);
    a2[1] = fmaf(y.y, w, a2[1]);
    a2[2] = fmaf(y.z, w, a2[2]);
    a2[3] = fmaf(y.w, w, a2[3]);
  }
  __syncthreads();  // done reading hA before anyone... (hB distinct; sync for hB write->read order below)
  {
    const float bm = bm2[j];
    float4 h;
    h.x = fmaxf(a2[0] + bm, 0.f);
    h.y = fmaxf(a2[1] + bm, 0.f);
    h.z = fmaxf(a2[2] + bm, 0.f);
    h.w = fmaxf(a2[3] + bm, 0.f);
    *(float4*)&hB[j][gh << 2] = h;
  }
  __syncthreads();

  float a3r[4] = {0.f, 0.f, 0.f, 0.f};
  for (int k = 0; k < 256; ++k) {
    const float4 y = *(const float4*)&hB[k][gh << 2];
    const float w = wm3[(k << 8) + j];
    a3r[0] = fmaf(y.x, w, a3r[0]);
    a3r[1] = fmaf(y.y, w, a3r[1]);
    a3r[2] = fmaf(y.z, w, a3r[2]);
    a3r[3] = fmaf(y.w, w, a3r[3]);
  }
  __syncthreads();  // hA fully consumed earlier; safe to overwrite after this
  {
    const float bm = bm3[j];
    float4 h;
    h.x = fmaxf(a3r[0] + bm, 0.f);
    h.y = fmaxf(a3r[1] + bm, 0.f);
    h.z = fmaxf(a3r[2] + bm, 0.f);
    h.w = fmaxf(a3r[3] + bm, 0.f);
    *(float4*)&hA[j][gh << 2] = h;  // h3, transposed [k][g]
  }
  __syncthreads();

  if (tid < 128) {
    const int g = tid >> 4, jj = tid & 15;
    float lg = bp[jj];
    for (int k = 0; k < 256; ++k)
      lg = fmaf(hA[k][g], wp[(k << 4) + jj], lg);
    float m = lg;
#pragma unroll
    for (int off = 1; off < 16; off <<= 1) m = fmaxf(m, __shfl_xor(m, off));
    const float e = expf(lg - m);
    float se = e;
#pragma unroll
    for (int off = 1; off < 16; off <<= 1) se += __shfl_xor(se, off);
    out[((b0 + g) << 4) + jj] = (lg - m) - logf(se);
  }
}

// ---------------------------------------------------------------------------
extern "C" void kernel_launch(void* const* d_in, const int* in_sizes, int n_in,
                              void* d_out, int out_size, void* d_ws, size_t ws_size,
                              hipStream_t stream)
{
  const float* x   = (const float*)d_in[0];
  const int*   ei  = (const int*)d_in[1];
  const float* w1  = (const float*)d_in[2];
  const float* b1  = (const float*)d_in[3];
  const float* w2  = (const float*)d_in[4];
  const float* b2  = (const float*)d_in[5];
  const float* c2w = (const float*)d_in[6];
  const float* c2b = (const float*)d_in[7];
  const float* c3w = (const float*)d_in[8];
  const float* c3b = (const float*)d_in[9];
  const float* g1  = (const float*)d_in[10];
  const float* be1 = (const float*)d_in[11];
  const float* g2  = (const float*)d_in[12];
  const float* be2 = (const float*)d_in[13];
  const float* g3  = (const float*)d_in[14];
  const float* be3 = (const float*)d_in[15];
  const float* wm1 = (const float*)d_in[16];
  const float* bm1 = (const float*)d_in[17];
  const float* wm2 = (const float*)d_in[18];
  const float* bm2 = (const float*)d_in[19];
  const float* wm3 = (const float*)d_in[20];
  const float* bm3 = (const float*)d_in[21];
  const float* wp  = (const float*)d_in[22];
  const float* bp  = (const float*)d_in[23];

  char* ws = (char*)d_ws;
  float* buf0 = (float*)ws;                        // 16 MiB: out0, later z3
  float* buf1 = (float*)(ws + ((size_t)16 << 20)); // 16 MiB: z2
  float* stats = (float*)(ws + ((size_t)32 << 20));
  float* stats1 = stats;
  float* stats2 = stats + 128;
  float* stats3 = stats + 256;

  hipMemsetAsync(stats, 0, 3 * 128 * sizeof(float), stream);
  k_edge<<<dim3(NB), dim3(256), 0, stream>>>(x, ei, w1, b1, w2, b2, buf0, stats1);
  k_conv<<<dim3(NB), dim3(256), 0, stream>>>(buf0, 1, stats1, g1, be1, c2w, c2b, buf1, stats2);
  k_conv<<<dim3(NB), dim3(256), 0, stream>>>(buf1, 0, stats2, g2, be2, c3w, c3b, buf0, stats3);
  k_mlp<<<dim3(128), dim3(512), 0, stream>>>(buf0, stats3, g3, be3,
                                             wm1, bm1, wm2, bm2, wm3, bm3, wp, bp,
                                             (float*)d_out);
}

// Round 2
// 325.111 us; speedup vs baseline: 1.3273x; 1.3273x over previous
//
#include <hip/hip_runtime.h>
#include <cstdint>
#include <cstddef>

typedef __attribute__((ext_vector_type(8))) short short8;
typedef __attribute__((ext_vector_type(4))) float f32x4;

#define EPSV 1e-5f
#define NB 1024
#define NEDGE 1048576
#define EPG 1024
#define CNTF 65536.0f

__device__ __forceinline__ ushort f2bf(float f) {
  uint u = __float_as_uint(f);
  return (ushort)((u + 0x7FFFu + ((u >> 16) & 1u)) >> 16);
}

// ---------------------------------------------------------------------------
// Stage 1: EdgeConv. One block per graph. (unchanged from round 1)
// ---------------------------------------------------------------------------
__global__ __launch_bounds__(256) void k_edge(
    const float* __restrict__ x, const int* __restrict__ ei,
    const float* __restrict__ w1, const float* __restrict__ b1,
    const float* __restrict__ w2, const float* __restrict__ b2,
    float* __restrict__ out0, float* __restrict__ stats1)
{
  __shared__ float xs[64];
  __shared__ float agg[64][8];
  __shared__ float w1s[8], b1s[4];
  __shared__ float w2s[256], b2s[64];
  __shared__ float rs[4][64], rss[4][64];
  const int tid = threadIdx.x;
  const int b = blockIdx.x;

  if (tid < 8) w1s[tid] = w1[tid];
  if (tid < 4) b1s[tid] = b1[tid];
  if (tid < 64) { xs[tid] = x[(b << 6) + tid]; b2s[tid] = b2[tid]; }
  w2s[tid] = w2[tid];
  for (int i = tid; i < 512; i += 256) ((float*)agg)[i] = 0.f;
  __syncthreads();

  const int e0 = b * EPG;
  for (int i = tid; i < EPG; i += 256) {
    const int e = e0 + i;
    const int sl = ei[e] & 63;
    const int dl = ei[NEDGE + e] & 63;
    const float xi = xs[dl];
    const float dx = xs[sl] - xi;
#pragma unroll
    for (int j = 0; j < 4; ++j) {
      float h = fmaxf(fmaf(xi, w1s[j], fmaf(dx, w1s[4 + j], b1s[j])), 0.f);
      atomicAdd(&agg[dl][j], h);
    }
    atomicAdd(&agg[dl][4], 1.0f);
  }
  __syncthreads();

  const int c = tid & 63, q = tid >> 6;
  const float wc0 = w2s[c], wc1 = w2s[64 + c], wc2 = w2s[128 + c], wc3 = w2s[192 + c];
  const float b2c = b2s[c];
  float s = 0.f, ss = 0.f;
  for (int n = q; n < 64; n += 4) {
    float v = agg[n][0] * wc0 + agg[n][1] * wc1 + agg[n][2] * wc2 +
              agg[n][3] * wc3 + agg[n][4] * b2c;
    out0[(size_t)(((b << 6) + n) << 6) + c] = v;
    s += v; ss += v * v;
  }
  rs[q][c] = s; rss[q][c] = ss;
  __syncthreads();
  if (tid < 64) {
    atomicAdd(&stats1[tid], rs[0][tid] + rs[1][tid] + rs[2][tid] + rs[3][tid]);
    atomicAdd(&stats1[64 + tid], rss[0][tid] + rss[1][tid] + rss[2][tid] + rss[3][tid]);
  }
}

// ---------------------------------------------------------------------------
// Stage 2/3: BN+ReLU + Conv1d(64,64,3,pad=1) + BN-stat accumulation.
// (unchanged from round 1)
// ---------------------------------------------------------------------------
__global__ __launch_bounds__(256) void k_conv(
    const float* __restrict__ in, const int transpose_in,
    const float* __restrict__ stats_in,
    const float* __restrict__ gamma, const float* __restrict__ beta,
    const float* __restrict__ cw, const float* __restrict__ cb,
    float* __restrict__ out, float* __restrict__ stats_out)
{
  __shared__ float Wt[96][66];
  __shared__ float Y[64][66];
  __shared__ float aco[64], bco[64], cbs[64];
  __shared__ float ldsS[64], ldsSS[64];
  const int tid = threadIdx.x;
  const int b = blockIdx.x;

  if (tid < 64) {
    const float sm = stats_in[tid], sq = stats_in[64 + tid];
    const float mean = sm * (1.0f / CNTF);
    const float var = sq * (1.0f / CNTF) - mean * mean;
    const float a = gamma[tid] * rsqrtf(var + EPSV);
    aco[tid] = a;
    bco[tid] = beta[tid] - mean * a;
    cbs[tid] = cb[tid];
    Y[tid][0] = 0.f;
    Y[tid][65] = 0.f;
  }
  __syncthreads();

  const size_t base = (size_t)b << 12;
  if (transpose_in) {
    for (int idx = tid; idx < 4096; idx += 256) {
      const int l = idx >> 6, c = idx & 63;
      const float v = in[base + idx];
      Y[c][l + 1] = fmaxf(fmaf(aco[c], v, bco[c]), 0.f);
    }
  } else {
    for (int idx = tid; idx < 4096; idx += 256) {
      const int c = idx >> 6, l = idx & 63;
      const float v = in[base + idx];
      Y[c][l + 1] = fmaxf(fmaf(aco[c], v, bco[c]), 0.f);
    }
  }
  for (int idx = tid; idx < 6144; idx += 256) {
    const int o = idx / 96, r = idx - o * 96;
    Wt[r][o] = cw[o * 192 + r];
  }
  __syncthreads();

  const int tl = tid & 15, to = tid >> 4;
  const int lbase = tl << 2, obase = to << 2;
  float acc[4][4];
#pragma unroll
  for (int i = 0; i < 4; ++i) {
    const float cbv = cbs[obase + i];
#pragma unroll
    for (int jj = 0; jj < 4; ++jj) acc[i][jj] = cbv;
  }

#pragma unroll 1
  for (int half = 0; half < 2; ++half) {
    if (half == 1) {
      __syncthreads();
      for (int idx = tid; idx < 6144; idx += 256) {
        const int o = idx / 96, r = idx - o * 96;
        Wt[r][o] = cw[o * 192 + 96 + r];
      }
      __syncthreads();
    }
    const int cbase = half << 5;
    for (int cc = 0; cc < 32; ++cc) {
      const int cg = cbase + cc;
      const float2 y01 = *(const float2*)&Y[cg][lbase];
      const float2 y23 = *(const float2*)&Y[cg][lbase + 2];
      const float2 y45 = *(const float2*)&Y[cg][lbase + 4];
      const float yv[6] = {y01.x, y01.y, y23.x, y23.y, y45.x, y45.y};
#pragma unroll
      for (int k = 0; k < 3; ++k) {
        const float2 wa = *(const float2*)&Wt[cc * 3 + k][obase];
        const float2 wb = *(const float2*)&Wt[cc * 3 + k][obase + 2];
#pragma unroll
        for (int jj = 0; jj < 4; ++jj) {
          const float yy = yv[jj + k];
          acc[0][jj] = fmaf(wa.x, yy, acc[0][jj]);
          acc[1][jj] = fmaf(wa.y, yy, acc[1][jj]);
          acc[2][jj] = fmaf(wb.x, yy, acc[2][jj]);
          acc[3][jj] = fmaf(wb.y, yy, acc[3][jj]);
        }
      }
    }
  }

#pragma unroll
  for (int i = 0; i < 4; ++i) {
    const int o = obase + i;
    float4 v4 = make_float4(acc[i][0], acc[i][1], acc[i][2], acc[i][3]);
    *(float4*)&out[base + (size_t)(o << 6) + lbase] = v4;
    float s = acc[i][0] + acc[i][1] + acc[i][2] + acc[i][3];
    float ssq = acc[i][0] * acc[i][0] + acc[i][1] * acc[i][1] +
                acc[i][2] * acc[i][2] + acc[i][3] * acc[i][3];
#pragma unroll
    for (int off = 1; off < 16; off <<= 1) {
      s += __shfl_xor(s, off);
      ssq += __shfl_xor(ssq, off);
    }
    if (tl == 0) { ldsS[o] = s; ldsSS[o] = ssq; }
  }
  __syncthreads();
  if (tid < 64) {
    atomicAdd(&stats_out[tid], ldsS[tid]);
    atomicAdd(&stats_out[64 + tid], ldsSS[tid]);
  }
}

// ---------------------------------------------------------------------------
// k_prep: wm1 fp32 [4096][256] -> bf16 (RNE). 1M elems, 256x256 grid.
// ---------------------------------------------------------------------------
__global__ __launch_bounds__(256) void k_prep(
    const float* __restrict__ wm1, ushort* __restrict__ wbf)
{
  const int gid = blockIdx.x * 256 + threadIdx.x;
  const float4* src = (const float4*)wm1;
  ushort4* dst = (ushort4*)wbf;
#pragma unroll
  for (int i = 0; i < 4; ++i) {
    const int idx = (i << 16) + gid;   // 262144 float4 total
    float4 v = src[idx];
    dst[idx] = make_ushort4(f2bf(v.x), f2bf(v.y), f2bf(v.z), f2bf(v.w));
  }
}

// ---------------------------------------------------------------------------
// k_mlp1: h1pre += (BN3+ReLU(z3)) @ wm1   via bf16 MFMA 16x16x32.
// Grid (16 Mtiles of 64 graphs, 4 Ntiles of 64 cols, 8 Ksplits of 512).
// Block = 256 thr = 4 waves; wave w owns m-rows w*16..w*16+15 x all 64 n.
// K-chunk = 64 (one BN channel per chunk). LDS: Ys[m][k], Ws[n][k] bf16,
// pitch 72 (16B-aligned rows, conflict-minimal b128 frag reads).
// Epilogue: fp32 atomicAdd into h1pre[g][n].
// ---------------------------------------------------------------------------
__global__ __launch_bounds__(256) void k_mlp1(
    const float* __restrict__ z3, const float* __restrict__ stats3,
    const float* __restrict__ g3, const float* __restrict__ be3,
    const ushort* __restrict__ wbf, float* __restrict__ h1pre)
{
  __shared__ ushort Ys[64][72];
  __shared__ ushort Ws[64][72];
  __shared__ float a3[64], b3[64];
  const int tid = threadIdx.x;
  const int bx = blockIdx.x, by = blockIdx.y, bz = blockIdx.z;

  if (tid < 64) {
    const float sm = stats3[tid], sq = stats3[64 + tid];
    const float mean = sm * (1.0f / CNTF);
    const float var = sq * (1.0f / CNTF) - mean * mean;
    const float a = g3[tid] * rsqrtf(var + EPSV);
    a3[tid] = a;
    b3[tid] = be3[tid] - mean * a;
  }
  __syncthreads();

  const int lane = tid & 63, w = tid >> 6;
  const int lm = lane & 15, q = lane >> 4;
  const int ry = tid >> 2, cy = (tid & 3) << 4;            // Y staging map
  const int ngr = (tid & 15) << 2, kgr = (tid >> 4) << 2;  // W staging map
  const int g0 = bx << 6, n0 = by << 6;

  f32x4 acc[4];
#pragma unroll
  for (int nt = 0; nt < 4; ++nt) acc[nt] = (f32x4){0.f, 0.f, 0.f, 0.f};

  const size_t ybase = (size_t)(g0 + ry) << 12;

#pragma unroll 1
  for (int ck = 0; ck < 8; ++ck) {
    const int kc = (bz << 9) + (ck << 6);
    if (ck) __syncthreads();
    // --- stage Y (BN3+ReLU, fp32->bf16); whole chunk shares channel kc>>6
    const float sa = a3[kc >> 6], sb = b3[kc >> 6];
#pragma unroll
    for (int i = 0; i < 4; ++i) {
      const float4 v = *(const float4*)&z3[ybase + kc + cy + (i << 2)];
      *(ushort4*)&Ys[ry][cy + (i << 2)] = make_ushort4(
          f2bf(fmaxf(fmaf(sa, v.x, sb), 0.f)),
          f2bf(fmaxf(fmaf(sa, v.y, sb), 0.f)),
          f2bf(fmaxf(fmaf(sa, v.z, sb), 0.f)),
          f2bf(fmaxf(fmaf(sa, v.w, sb), 0.f)));
    }
    // --- stage W (bf16, [k][n] -> [n][k] 4x4 register transpose)
    {
      const ushort* wp0 = wbf + (((size_t)(kc + kgr)) << 8) + n0 + ngr;
      const ushort4 w0 = *(const ushort4*)(wp0);
      const ushort4 w1 = *(const ushort4*)(wp0 + 256);
      const ushort4 w2 = *(const ushort4*)(wp0 + 512);
      const ushort4 w3 = *(const ushort4*)(wp0 + 768);
      *(ushort4*)&Ws[ngr + 0][kgr] = make_ushort4(w0.x, w1.x, w2.x, w3.x);
      *(ushort4*)&Ws[ngr + 1][kgr] = make_ushort4(w0.y, w1.y, w2.y, w3.y);
      *(ushort4*)&Ws[ngr + 2][kgr] = make_ushort4(w0.z, w1.z, w2.z, w3.z);
      *(ushort4*)&Ws[ngr + 3][kgr] = make_ushort4(w0.w, w1.w, w2.w, w3.w);
    }
    __syncthreads();
    // --- MFMA: 2 k-steps of 32, 4 n-tiles of 16
#pragma unroll
    for (int ks = 0; ks < 2; ++ks) {
      const short8 af = *(const short8*)&Ys[(w << 4) + lm][(ks << 5) + (q << 3)];
#pragma unroll
      for (int nt = 0; nt < 4; ++nt) {
        const short8 bfr = *(const short8*)&Ws[(nt << 4) + lm][(ks << 5) + (q << 3)];
        acc[nt] = __builtin_amdgcn_mfma_f32_16x16x32_bf16(af, bfr, acc[nt], 0, 0, 0);
      }
    }
  }

  // epilogue: C/D layout col=lane&15, row=(lane>>4)*4+reg
  const int gout = g0 + (w << 4) + (q << 2);
#pragma unroll
  for (int nt = 0; nt < 4; ++nt) {
    const int col = n0 + (nt << 4) + lm;
#pragma unroll
    for (int i = 0; i < 4; ++i)
      atomicAdd(&h1pre[((size_t)(gout + i) << 8) + col], acc[nt][i]);
  }
}

// ---------------------------------------------------------------------------
// k_mlp2: bias+ReLU on h1pre, then 256->256->256->16 + log_softmax.
// 256 blocks x 4 graphs, 256 threads (thread = output col j, 4 graphs).
// LDS rows pitch-8 floats; inner reads are same-address float4 broadcasts.
// ---------------------------------------------------------------------------
__global__ __launch_bounds__(256) void k_mlp2(
    const float* __restrict__ h1pre, const float* __restrict__ bm1,
    const float* __restrict__ wm2, const float* __restrict__ bm2,
    const float* __restrict__ wm3, const float* __restrict__ bm3,
    const float* __restrict__ wp, const float* __restrict__ bp,
    float* __restrict__ out)
{
  __shared__ float hA[256][8];
  __shared__ float hB[256][8];
  const int tid = threadIdx.x;
  const int g0 = blockIdx.x << 2;

#pragma unroll
  for (int i = 0; i < 4; ++i) {
    const int flat = tid + (i << 8);
    const int g = flat >> 8, k = flat & 255;
    hA[k][g] = fmaxf(h1pre[((size_t)(g0 + g) << 8) + k] + bm1[k], 0.f);
  }
  __syncthreads();

  float a2[4] = {0.f, 0.f, 0.f, 0.f};
#pragma unroll 4
  for (int k = 0; k < 256; ++k) {
    const float4 y = *(const float4*)&hA[k][0];
    const float wv = wm2[(k << 8) + tid];
    a2[0] = fmaf(y.x, wv, a2[0]);
    a2[1] = fmaf(y.y, wv, a2[1]);
    a2[2] = fmaf(y.z, wv, a2[2]);
    a2[3] = fmaf(y.w, wv, a2[3]);
  }
  {
    const float bv = bm2[tid];
    *(float4*)&hB[tid][0] = make_float4(
        fmaxf(a2[0] + bv, 0.f), fmaxf(a2[1] + bv, 0.f),
        fmaxf(a2[2] + bv, 0.f), fmaxf(a2[3] + bv, 0.f));
  }
  __syncthreads();

  float a3r[4] = {0.f, 0.f, 0.f, 0.f};
#pragma unroll 4
  for (int k = 0; k < 256; ++k) {
    const float4 y = *(const float4*)&hB[k][0];
    const float wv = wm3[(k << 8) + tid];
    a3r[0] = fmaf(y.x, wv, a3r[0]);
    a3r[1] = fmaf(y.y, wv, a3r[1]);
    a3r[2] = fmaf(y.z, wv, a3r[2]);
    a3r[3] = fmaf(y.w, wv, a3r[3]);
  }
  {
    const float bv = bm3[tid];
    *(float4*)&hA[tid][0] = make_float4(
        fmaxf(a3r[0] + bv, 0.f), fmaxf(a3r[1] + bv, 0.f),
        fmaxf(a3r[2] + bv, 0.f), fmaxf(a3r[3] + bv, 0.f));
  }
  __syncthreads();

  if (tid < 64) {
    const int g = tid >> 4, jj = tid & 15;
    float lg = bp[jj];
#pragma unroll 4
    for (int k = 0; k < 256; ++k)
      lg = fmaf(hA[k][g], wp[(k << 4) + jj], lg);
    float m = lg;
#pragma unroll
    for (int off = 1; off < 16; off <<= 1) m = fmaxf(m, __shfl_xor(m, off));
    const float e = expf(lg - m);
    float se = e;
#pragma unroll
    for (int off = 1; off < 16; off <<= 1) se += __shfl_xor(se, off);
    out[((g0 + g) << 4) + jj] = (lg - m) - logf(se);
  }
}

// ---------------------------------------------------------------------------
extern "C" void kernel_launch(void* const* d_in, const int* in_sizes, int n_in,
                              void* d_out, int out_size, void* d_ws, size_t ws_size,
                              hipStream_t stream)
{
  const float* x   = (const float*)d_in[0];
  const int*   ei  = (const int*)d_in[1];
  const float* w1  = (const float*)d_in[2];
  const float* b1  = (const float*)d_in[3];
  const float* w2  = (const float*)d_in[4];
  const float* b2  = (const float*)d_in[5];
  const float* c2w = (const float*)d_in[6];
  const float* c2b = (const float*)d_in[7];
  const float* c3w = (const float*)d_in[8];
  const float* c3b = (const float*)d_in[9];
  const float* g1  = (const float*)d_in[10];
  const float* be1 = (const float*)d_in[11];
  const float* g2  = (const float*)d_in[12];
  const float* be2 = (const float*)d_in[13];
  const float* g3  = (const float*)d_in[14];
  const float* be3 = (const float*)d_in[15];
  const float* wm1 = (const float*)d_in[16];
  const float* bm1 = (const float*)d_in[17];
  const float* wm2 = (const float*)d_in[18];
  const float* bm2 = (const float*)d_in[19];
  const float* wm3 = (const float*)d_in[20];
  const float* bm3 = (const float*)d_in[21];
  const float* wp  = (const float*)d_in[22];
  const float* bp  = (const float*)d_in[23];

  char* ws = (char*)d_ws;
  float* buf0 = (float*)ws;                        // 16 MiB: out0, later z3
  float* buf1 = (float*)(ws + ((size_t)16 << 20)); // 16 MiB: z2; then h1pre+wbf
  float* stats = (float*)(ws + ((size_t)32 << 20));
  float* stats1 = stats;
  float* stats2 = stats + 128;
  float* stats3 = stats + 256;
  float*  h1pre = buf1;                                  // 1 MiB (reuses z2 space)
  ushort* wbf   = (ushort*)(ws + ((size_t)17 << 20));    // 2 MiB bf16 wm1

  hipMemsetAsync(stats, 0, 3 * 128 * sizeof(float), stream);
  k_edge<<<dim3(NB), dim3(256), 0, stream>>>(x, ei, w1, b1, w2, b2, buf0, stats1);
  k_conv<<<dim3(NB), dim3(256), 0, stream>>>(buf0, 1, stats1, g1, be1, c2w, c2b, buf1, stats2);
  k_conv<<<dim3(NB), dim3(256), 0, stream>>>(buf1, 0, stats2, g2, be2, c3w, c3b, buf0, stats3);
  // z2 (buf1) is dead after the second k_conv: reuse its space for h1pre+wbf
  hipMemsetAsync(h1pre, 0, (size_t)1024 * 256 * sizeof(float), stream);
  k_prep<<<dim3(256), dim3(256), 0, stream>>>(wm1, wbf);
  k_mlp1<<<dim3(16, 4, 8), dim3(256), 0, stream>>>(buf0, stats3, g3, be3, wbf, h1pre);
  k_mlp2<<<dim3(256), dim3(256), 0, stream>>>(h1pre, bm1, wm2, bm2, wm3, bm3, wp, bp,
                                              (float*)d_out);
}

// Round 3
// 284.350 us; speedup vs baseline: 1.5176x; 1.1433x over previous
//
#include <hip/hip_runtime.h>
#include <cstdint>
#include <cstddef>

typedef __attribute__((ext_vector_type(8))) short short8;
typedef __attribute__((ext_vector_type(4))) float f32x4;

#define EPSV 1e-5f
#define NB 1024
#define NEDGE 1048576
#define EPG 1024
#define CNTF 65536.0f

__device__ __forceinline__ ushort f2bf(float f) {
  uint u = __float_as_uint(f);
  return (ushort)((u + 0x7FFFu + ((u >> 16) & 1u)) >> 16);
}

// ---------------------------------------------------------------------------
// Stage 1: EdgeConv. One block per graph. (unchanged)
// ---------------------------------------------------------------------------
__global__ __launch_bounds__(256) void k_edge(
    const float* __restrict__ x, const int* __restrict__ ei,
    const float* __restrict__ w1, const float* __restrict__ b1,
    const float* __restrict__ w2, const float* __restrict__ b2,
    float* __restrict__ out0, float* __restrict__ stats1)
{
  __shared__ float xs[64];
  __shared__ float agg[64][8];
  __shared__ float w1s[8], b1s[4];
  __shared__ float w2s[256], b2s[64];
  __shared__ float rs[4][64], rss[4][64];
  const int tid = threadIdx.x;
  const int b = blockIdx.x;

  if (tid < 8) w1s[tid] = w1[tid];
  if (tid < 4) b1s[tid] = b1[tid];
  if (tid < 64) { xs[tid] = x[(b << 6) + tid]; b2s[tid] = b2[tid]; }
  w2s[tid] = w2[tid];
  for (int i = tid; i < 512; i += 256) ((float*)agg)[i] = 0.f;
  __syncthreads();

  const int e0 = b * EPG;
  for (int i = tid; i < EPG; i += 256) {
    const int e = e0 + i;
    const int sl = ei[e] & 63;
    const int dl = ei[NEDGE + e] & 63;
    const float xi = xs[dl];
    const float dx = xs[sl] - xi;
#pragma unroll
    for (int j = 0; j < 4; ++j) {
      float h = fmaxf(fmaf(xi, w1s[j], fmaf(dx, w1s[4 + j], b1s[j])), 0.f);
      atomicAdd(&agg[dl][j], h);
    }
    atomicAdd(&agg[dl][4], 1.0f);
  }
  __syncthreads();

  const int c = tid & 63, q = tid >> 6;
  const float wc0 = w2s[c], wc1 = w2s[64 + c], wc2 = w2s[128 + c], wc3 = w2s[192 + c];
  const float b2c = b2s[c];
  float s = 0.f, ss = 0.f;
  for (int n = q; n < 64; n += 4) {
    float v = agg[n][0] * wc0 + agg[n][1] * wc1 + agg[n][2] * wc2 +
              agg[n][3] * wc3 + agg[n][4] * b2c;
    out0[(size_t)(((b << 6) + n) << 6) + c] = v;
    s += v; ss += v * v;
  }
  rs[q][c] = s; rss[q][c] = ss;
  __syncthreads();
  if (tid < 64) {
    atomicAdd(&stats1[tid], rs[0][tid] + rs[1][tid] + rs[2][tid] + rs[3][tid]);
    atomicAdd(&stats1[64 + tid], rss[0][tid] + rss[1][tid] + rss[2][tid] + rss[3][tid]);
  }
}

// ---------------------------------------------------------------------------
// Stage 2/3: BN+ReLU + Conv1d(64,64,3,pad=1) + BN stats. (unchanged)
// ---------------------------------------------------------------------------
__global__ __launch_bounds__(256) void k_conv(
    const float* __restrict__ in, const int transpose_in,
    const float* __restrict__ stats_in,
    const float* __restrict__ gamma, const float* __restrict__ beta,
    const float* __restrict__ cw, const float* __restrict__ cb,
    float* __restrict__ out, float* __restrict__ stats_out)
{
  __shared__ float Wt[96][66];
  __shared__ float Y[64][66];
  __shared__ float aco[64], bco[64], cbs[64];
  __shared__ float ldsS[64], ldsSS[64];
  const int tid = threadIdx.x;
  const int b = blockIdx.x;

  if (tid < 64) {
    const float sm = stats_in[tid], sq = stats_in[64 + tid];
    const float mean = sm * (1.0f / CNTF);
    const float var = sq * (1.0f / CNTF) - mean * mean;
    const float a = gamma[tid] * rsqrtf(var + EPSV);
    aco[tid] = a;
    bco[tid] = beta[tid] - mean * a;
    cbs[tid] = cb[tid];
    Y[tid][0] = 0.f;
    Y[tid][65] = 0.f;
  }
  __syncthreads();

  const size_t base = (size_t)b << 12;
  if (transpose_in) {
    for (int idx = tid; idx < 4096; idx += 256) {
      const int l = idx >> 6, c = idx & 63;
      const float v = in[base + idx];
      Y[c][l + 1] = fmaxf(fmaf(aco[c], v, bco[c]), 0.f);
    }
  } else {
    for (int idx = tid; idx < 4096; idx += 256) {
      const int c = idx >> 6, l = idx & 63;
      const float v = in[base + idx];
      Y[c][l + 1] = fmaxf(fmaf(aco[c], v, bco[c]), 0.f);
    }
  }
  for (int idx = tid; idx < 6144; idx += 256) {
    const int o = idx / 96, r = idx - o * 96;
    Wt[r][o] = cw[o * 192 + r];
  }
  __syncthreads();

  const int tl = tid & 15, to = tid >> 4;
  const int lbase = tl << 2, obase = to << 2;
  float acc[4][4];
#pragma unroll
  for (int i = 0; i < 4; ++i) {
    const float cbv = cbs[obase + i];
#pragma unroll
    for (int jj = 0; jj < 4; ++jj) acc[i][jj] = cbv;
  }

#pragma unroll 1
  for (int half = 0; half < 2; ++half) {
    if (half == 1) {
      __syncthreads();
      for (int idx = tid; idx < 6144; idx += 256) {
        const int o = idx / 96, r = idx - o * 96;
        Wt[r][o] = cw[o * 192 + 96 + r];
      }
      __syncthreads();
    }
    const int cbase = half << 5;
    for (int cc = 0; cc < 32; ++cc) {
      const int cg = cbase + cc;
      const float2 y01 = *(const float2*)&Y[cg][lbase];
      const float2 y23 = *(const float2*)&Y[cg][lbase + 2];
      const float2 y45 = *(const float2*)&Y[cg][lbase + 4];
      const float yv[6] = {y01.x, y01.y, y23.x, y23.y, y45.x, y45.y};
#pragma unroll
      for (int k = 0; k < 3; ++k) {
        const float2 wa = *(const float2*)&Wt[cc * 3 + k][obase];
        const float2 wb = *(const float2*)&Wt[cc * 3 + k][obase + 2];
#pragma unroll
        for (int jj = 0; jj < 4; ++jj) {
          const float yy = yv[jj + k];
          acc[0][jj] = fmaf(wa.x, yy, acc[0][jj]);
          acc[1][jj] = fmaf(wa.y, yy, acc[1][jj]);
          acc[2][jj] = fmaf(wb.x, yy, acc[2][jj]);
          acc[3][jj] = fmaf(wb.y, yy, acc[3][jj]);
        }
      }
    }
  }

#pragma unroll
  for (int i = 0; i < 4; ++i) {
    const int o = obase + i;
    float4 v4 = make_float4(acc[i][0], acc[i][1], acc[i][2], acc[i][3]);
    *(float4*)&out[base + (size_t)(o << 6) + lbase] = v4;
    float s = acc[i][0] + acc[i][1] + acc[i][2] + acc[i][3];
    float ssq = acc[i][0] * acc[i][0] + acc[i][1] * acc[i][1] +
                acc[i][2] * acc[i][2] + acc[i][3] * acc[i][3];
#pragma unroll
    for (int off = 1; off < 16; off <<= 1) {
      s += __shfl_xor(s, off);
      ssq += __shfl_xor(ssq, off);
    }
    if (tl == 0) { ldsS[o] = s; ldsSS[o] = ssq; }
  }
  __syncthreads();
  if (tid < 64) {
    atomicAdd(&stats_out[tid], ldsS[tid]);
    atomicAdd(&stats_out[64 + tid], ldsSS[tid]);
  }
}

// ---------------------------------------------------------------------------
// k_prep: wm1 fp32 [4096][256] -> bf16 (RNE). (unchanged)
// ---------------------------------------------------------------------------
__global__ __launch_bounds__(256) void k_prep(
    const float* __restrict__ wm1, ushort* __restrict__ wbf)
{
  const int gid = blockIdx.x * 256 + threadIdx.x;
  const float4* src = (const float4*)wm1;
  ushort4* dst = (ushort4*)wbf;
#pragma unroll
  for (int i = 0; i < 4; ++i) {
    const int idx = (i << 16) + gid;
    float4 v = src[idx];
    dst[idx] = make_ushort4(f2bf(v.x), f2bf(v.y), f2bf(v.z), f2bf(v.w));
  }
}

// ---------------------------------------------------------------------------
// k_prep2: wm2,wm3 fp32 [256k][256n] -> bf16 transposed chunk-major layout
// [kc][n][kk] (kc=k>>6, kk=k&63) so a 64-k chunk is one contiguous 32KB blob.
// Also wp [256k][16a] -> bf16 wpt [a][k] (block 64).
// Grid 65 x 256.
// ---------------------------------------------------------------------------
__global__ __launch_bounds__(256) void k_prep2(
    const float* __restrict__ wm2, const float* __restrict__ wm3,
    const float* __restrict__ wp,
    ushort* __restrict__ wbf2t, ushort* __restrict__ wbf3t,
    ushort* __restrict__ wptbf)
{
  const int tid = threadIdx.x;
  if (blockIdx.x == 64) {
    // wp^T: thread t -> a = t&15, k-range (t>>4)*16..+15
    const int a = tid & 15, k0 = (tid >> 4) << 4;
    ushort tmp[16];
#pragma unroll
    for (int j = 0; j < 16; ++j) tmp[j] = f2bf(wp[((k0 + j) << 4) + a]);
    *(short8*)&wptbf[(a << 8) + k0] = *(short8*)&tmp[0];
    *(short8*)&wptbf[(a << 8) + k0 + 8] = *(short8*)&tmp[8];
    return;
  }
  const int base = ((blockIdx.x << 8) + tid) << 3;  // 8 outputs per thread
  const int m = base >> 16;
  const int rem = base & 65535;
  const int kc = rem >> 14, within = rem & 16383;
  const int n = within >> 6, kk0 = within & 63;
  const float* src = m ? wm3 : wm2;
  ushort* dst = m ? wbf3t : wbf2t;
  ushort tmp[8];
#pragma unroll
  for (int j = 0; j < 8; ++j)
    tmp[j] = f2bf(src[(((kc << 6) | (kk0 + j)) << 8) + n]);
  *(short8*)&dst[rem] = *(short8*)&tmp[0];
}

// ---------------------------------------------------------------------------
// k_mlp1: h1pre += (BN3+ReLU(z3)) @ wm1 via bf16 MFMA 16x16x32. (unchanged)
// ---------------------------------------------------------------------------
__global__ __launch_bounds__(256) void k_mlp1(
    const float* __restrict__ z3, const float* __restrict__ stats3,
    const float* __restrict__ g3, const float* __restrict__ be3,
    const ushort* __restrict__ wbf, float* __restrict__ h1pre)
{
  __shared__ ushort Ys[64][72];
  __shared__ ushort Ws[64][72];
  __shared__ float a3[64], b3[64];
  const int tid = threadIdx.x;
  const int bx = blockIdx.x, by = blockIdx.y, bz = blockIdx.z;

  if (tid < 64) {
    const float sm = stats3[tid], sq = stats3[64 + tid];
    const float mean = sm * (1.0f / CNTF);
    const float var = sq * (1.0f / CNTF) - mean * mean;
    const float a = g3[tid] * rsqrtf(var + EPSV);
    a3[tid] = a;
    b3[tid] = be3[tid] - mean * a;
  }
  __syncthreads();

  const int lane = tid & 63, w = tid >> 6;
  const int lm = lane & 15, q = lane >> 4;
  const int ry = tid >> 2, cy = (tid & 3) << 4;
  const int ngr = (tid & 15) << 2, kgr = (tid >> 4) << 2;
  const int g0 = bx << 6, n0 = by << 6;

  f32x4 acc[4];
#pragma unroll
  for (int nt = 0; nt < 4; ++nt) acc[nt] = (f32x4){0.f, 0.f, 0.f, 0.f};

  const size_t ybase = (size_t)(g0 + ry) << 12;

#pragma unroll 1
  for (int ck = 0; ck < 8; ++ck) {
    const int kc = (bz << 9) + (ck << 6);
    if (ck) __syncthreads();
    const float sa = a3[kc >> 6], sb = b3[kc >> 6];
#pragma unroll
    for (int i = 0; i < 4; ++i) {
      const float4 v = *(const float4*)&z3[ybase + kc + cy + (i << 2)];
      *(ushort4*)&Ys[ry][cy + (i << 2)] = make_ushort4(
          f2bf(fmaxf(fmaf(sa, v.x, sb), 0.f)),
          f2bf(fmaxf(fmaf(sa, v.y, sb), 0.f)),
          f2bf(fmaxf(fmaf(sa, v.z, sb), 0.f)),
          f2bf(fmaxf(fmaf(sa, v.w, sb), 0.f)));
    }
    {
      const ushort* wp0 = wbf + (((size_t)(kc + kgr)) << 8) + n0 + ngr;
      const ushort4 w0 = *(const ushort4*)(wp0);
      const ushort4 w1 = *(const ushort4*)(wp0 + 256);
      const ushort4 w2 = *(const ushort4*)(wp0 + 512);
      const ushort4 w3 = *(const ushort4*)(wp0 + 768);
      *(ushort4*)&Ws[ngr + 0][kgr] = make_ushort4(w0.x, w1.x, w2.x, w3.x);
      *(ushort4*)&Ws[ngr + 1][kgr] = make_ushort4(w0.y, w1.y, w2.y, w3.y);
      *(ushort4*)&Ws[ngr + 2][kgr] = make_ushort4(w0.z, w1.z, w2.z, w3.z);
      *(ushort4*)&Ws[ngr + 3][kgr] = make_ushort4(w0.w, w1.w, w2.w, w3.w);
    }
    __syncthreads();
#pragma unroll
    for (int ks = 0; ks < 2; ++ks) {
      const short8 af = *(const short8*)&Ys[(w << 4) + lm][(ks << 5) + (q << 3)];
#pragma unroll
      for (int nt = 0; nt < 4; ++nt) {
        const short8 bfr = *(const short8*)&Ws[(nt << 4) + lm][(ks << 5) + (q << 3)];
        acc[nt] = __builtin_amdgcn_mfma_f32_16x16x32_bf16(af, bfr, acc[nt], 0, 0, 0);
      }
    }
  }

  const int gout = g0 + (w << 4) + (q << 2);
#pragma unroll
  for (int nt = 0; nt < 4; ++nt) {
    const int col = n0 + (nt << 4) + lm;
#pragma unroll
    for (int i = 0; i < 4; ++i)
      atomicAdd(&h1pre[((size_t)(gout + i) << 8) + col], acc[nt][i]);
  }
}

// ---------------------------------------------------------------------------
// k_tail: per-block chain for 16 graphs: h1=relu(h1pre+bm1) ->
// h2=relu(h1@wm2+bm2) -> h3=relu(h2@wm3+bm3) -> logits=h3@wp+bp ->
// log_softmax. All GEMMs bf16 MFMA 16x16x32; weights staged per 64-k chunk
// from pre-transposed chunk-contiguous bf16 (k_prep2). 64 blocks x 256 thr.
// Wave w owns cols w*64..w*64+63 (4 n-tiles); m = 16 graphs.
// ---------------------------------------------------------------------------
__global__ __launch_bounds__(256) void k_tail(
    const float* __restrict__ h1pre, const float* __restrict__ bm1,
    const ushort* __restrict__ wbf2t, const float* __restrict__ bm2,
    const ushort* __restrict__ wbf3t, const float* __restrict__ bm3,
    const ushort* __restrict__ wptbf, const float* __restrict__ bp,
    float* __restrict__ out)
{
  __shared__ ushort Ws[256][72];    // 36864B; reused for wpt at head
  __shared__ ushort h1s[16][264];   // 8448B
  __shared__ ushort h2s[16][264];   // 8448B; reused for h3 at head
  ushort* wpt = &Ws[0][0];          // [16][264] view for head
  const int tid = threadIdx.x;
  const int g0 = blockIdx.x << 4;
  const int lane = tid & 63, w = tid >> 6;
  const int lm = lane & 15, q = lane >> 4;
  const int gr = q << 2;

  // stage h1 = relu(h1pre + bm1) -> bf16
  {
    const int r = tid >> 4, c0 = (tid & 15) << 4;
    const float* src = h1pre + ((size_t)(g0 + r) << 8) + c0;
#pragma unroll
    for (int i = 0; i < 4; ++i) {
      const float4 v = *(const float4*)(src + (i << 2));
      const float4 bb = *(const float4*)(bm1 + c0 + (i << 2));
      *(ushort4*)&h1s[r][c0 + (i << 2)] = make_ushort4(
          f2bf(fmaxf(v.x + bb.x, 0.f)), f2bf(fmaxf(v.y + bb.y, 0.f)),
          f2bf(fmaxf(v.z + bb.z, 0.f)), f2bf(fmaxf(v.w + bb.w, 0.f)));
    }
  }

  // ---- GEMM2: h2 = relu(h1 @ wm2 + bm2)
  f32x4 acc[4];
#pragma unroll
  for (int nt = 0; nt < 4; ++nt) acc[nt] = (f32x4){0.f, 0.f, 0.f, 0.f};
#pragma unroll 1
  for (int ck = 0; ck < 4; ++ck) {
    __syncthreads();
    {
      const short8* gw = (const short8*)(wbf2t + (ck << 14));
#pragma unroll
      for (int i = 0; i < 8; ++i) {
        const int e8 = (i << 8) + tid;
        const int n = e8 >> 3, kk = (e8 & 7) << 3;
        *(short8*)&Ws[n][kk] = gw[e8];
      }
    }
    __syncthreads();
#pragma unroll
    for (int ks = 0; ks < 2; ++ks) {
      const short8 af = *(const short8*)&h1s[lm][(ck << 6) + (ks << 5) + (q << 3)];
#pragma unroll
      for (int nt = 0; nt < 4; ++nt) {
        const short8 bfr = *(const short8*)&Ws[(w << 6) + (nt << 4) + lm][(ks << 5) + (q << 3)];
        acc[nt] = __builtin_amdgcn_mfma_f32_16x16x32_bf16(af, bfr, acc[nt], 0, 0, 0);
      }
    }
  }
  // epilogue -> h2s bf16 (no sync needed: h2s only read after next barrier)
#pragma unroll
  for (int nt = 0; nt < 4; ++nt) {
    const int col = (w << 6) + (nt << 4) + lm;
    const float bv = bm2[col];
#pragma unroll
    for (int i = 0; i < 4; ++i)
      h2s[gr + i][col] = f2bf(fmaxf(acc[nt][i] + bv, 0.f));
  }

  // ---- GEMM3: h3 = relu(h2 @ wm3 + bm3)
  f32x4 acc2[4];
#pragma unroll
  for (int nt = 0; nt < 4; ++nt) acc2[nt] = (f32x4){0.f, 0.f, 0.f, 0.f};
#pragma unroll 1
  for (int ck = 0; ck < 4; ++ck) {
    __syncthreads();
    {
      const short8* gw = (const short8*)(wbf3t + (ck << 14));
#pragma unroll
      for (int i = 0; i < 8; ++i) {
        const int e8 = (i << 8) + tid;
        const int n = e8 >> 3, kk = (e8 & 7) << 3;
        *(short8*)&Ws[n][kk] = gw[e8];
      }
    }
    __syncthreads();
#pragma unroll
    for (int ks = 0; ks < 2; ++ks) {
      const short8 af = *(const short8*)&h2s[lm][(ck << 6) + (ks << 5) + (q << 3)];
#pragma unroll
      for (int nt = 0; nt < 4; ++nt) {
        const short8 bfr = *(const short8*)&Ws[(w << 6) + (nt << 4) + lm][(ks << 5) + (q << 3)];
        acc2[nt] = __builtin_amdgcn_mfma_f32_16x16x32_bf16(af, bfr, acc2[nt], 0, 0, 0);
      }
    }
  }

  __syncthreads();  // Ws + h2s now free to repurpose
  // stage wpt (bf16 wp^T [16 a][256 k]) into Ws region
  {
    const short8* gw = (const short8*)wptbf;
#pragma unroll
    for (int i = 0; i < 2; ++i) {
      const int e8 = (i << 8) + tid;         // 512 total
      const int flat = e8 << 3;
      const int a = flat >> 8, kk = flat & 255;
      *(short8*)&wpt[a * 264 + kk] = gw[e8];
    }
  }
  // h3 epilogue -> h2s (reused) bf16
#pragma unroll
  for (int nt = 0; nt < 4; ++nt) {
    const int col = (w << 6) + (nt << 4) + lm;
    const float bv = bm3[col];
#pragma unroll
    for (int i = 0; i < 4; ++i)
      h2s[gr + i][col] = f2bf(fmaxf(acc2[nt][i] + bv, 0.f));
  }
  __syncthreads();

  // ---- head + log_softmax (wave 0 only): logits = h3 @ wp^T + bp
  if (w == 0) {
    f32x4 lacc = (f32x4){0.f, 0.f, 0.f, 0.f};
#pragma unroll
    for (int ks = 0; ks < 8; ++ks) {
      const short8 af = *(const short8*)&h2s[lm][(ks << 5) + (q << 3)];
      const short8 bfr = *(const short8*)&wpt[lm * 264 + (ks << 5) + (q << 3)];
      lacc = __builtin_amdgcn_mfma_f32_16x16x32_bf16(af, bfr, lacc, 0, 0, 0);
    }
    // lane: col a = lm, rows g = q*4+i
    const float bpv = bp[lm];
    float lg[4], mx[4], se[4];
#pragma unroll
    for (int i = 0; i < 4; ++i) {
      lg[i] = lacc[i] + bpv;
      float m = lg[i];
#pragma unroll
      for (int off = 1; off < 16; off <<= 1) m = fmaxf(m, __shfl_xor(m, off));
      mx[i] = m;
      float e = expf(lg[i] - m);
#pragma unroll
      for (int off = 1; off < 16; off <<= 1) e += __shfl_xor(e, off);
      se[i] = e;
    }
#pragma unroll
    for (int i = 0; i < 4; ++i)
      out[((g0 + gr + i) << 4) + lm] = (lg[i] - mx[i]) - logf(se[i]);
  }
}

// ---------------------------------------------------------------------------
extern "C" void kernel_launch(void* const* d_in, const int* in_sizes, int n_in,
                              void* d_out, int out_size, void* d_ws, size_t ws_size,
                              hipStream_t stream)
{
  const float* x   = (const float*)d_in[0];
  const int*   ei  = (const int*)d_in[1];
  const float* w1  = (const float*)d_in[2];
  const float* b1  = (const float*)d_in[3];
  const float* w2  = (const float*)d_in[4];
  const float* b2  = (const float*)d_in[5];
  const float* c2w = (const float*)d_in[6];
  const float* c2b = (const float*)d_in[7];
  const float* c3w = (const float*)d_in[8];
  const float* c3b = (const float*)d_in[9];
  const float* g1  = (const float*)d_in[10];
  const float* be1 = (const float*)d_in[11];
  const float* g2  = (const float*)d_in[12];
  const float* be2 = (const float*)d_in[13];
  const float* g3  = (const float*)d_in[14];
  const float* be3 = (const float*)d_in[15];
  const float* wm1 = (const float*)d_in[16];
  const float* bm1 = (const float*)d_in[17];
  const float* wm2 = (const float*)d_in[18];
  const float* bm2 = (const float*)d_in[19];
  const float* wm3 = (const float*)d_in[20];
  const float* bm3 = (const float*)d_in[21];
  const float* wp  = (const float*)d_in[22];
  const float* bp  = (const float*)d_in[23];

  char* ws = (char*)d_ws;
  float* buf0 = (float*)ws;                        // 16 MiB: out0, later z3
  float* buf1 = (float*)(ws + ((size_t)16 << 20)); // z2; then h1pre
  float* stats = (float*)(ws + ((size_t)32 << 20));
  float* stats1 = stats;
  float* stats2 = stats + 128;
  float* stats3 = stats + 256;
  float*  h1pre = buf1;                                   // 1 MiB
  ushort* wbf   = (ushort*)(ws + ((size_t)17 << 20));     // 2 MiB bf16 wm1
  ushort* wbf2t = (ushort*)(ws + ((size_t)19 << 20));     // 128 KiB
  ushort* wbf3t = (ushort*)(ws + ((size_t)19 << 20) + (128 << 10)); // 128 KiB
  ushort* wptbf = (ushort*)(ws + ((size_t)19 << 20) + (256 << 10)); // 8 KiB

  hipMemsetAsync(stats, 0, 3 * 128 * sizeof(float), stream);
  k_edge<<<dim3(NB), dim3(256), 0, stream>>>(x, ei, w1, b1, w2, b2, buf0, stats1);
  k_conv<<<dim3(NB), dim3(256), 0, stream>>>(buf0, 1, stats1, g1, be1, c2w, c2b, buf1, stats2);
  k_conv<<<dim3(NB), dim3(256), 0, stream>>>(buf1, 0, stats2, g2, be2, c3w, c3b, buf0, stats3);
  hipMemsetAsync(h1pre, 0, (size_t)1024 * 256 * sizeof(float), stream);
  k_prep<<<dim3(256), dim3(256), 0, stream>>>(wm1, wbf);
  k_prep2<<<dim3(65), dim3(256), 0, stream>>>(wm2, wm3, wp, wbf2t, wbf3t, wptbf);
  k_mlp1<<<dim3(16, 4, 8), dim3(256), 0, stream>>>(buf0, stats3, g3, be3, wbf, h1pre);
  k_tail<<<dim3(64), dim3(256), 0, stream>>>(h1pre, bm1, wbf2t, bm2, wbf3t, bm3,
                                             wptbf, bp, (float*)d_out);
}

// Round 4
// 252.657 us; speedup vs baseline: 1.7080x; 1.1254x over previous
//
#include <hip/hip_runtime.h>
#include <cstdint>
#include <cstddef>

typedef __attribute__((ext_vector_type(8))) short short8;
typedef __attribute__((ext_vector_type(4))) float f32x4;

#define EPSV 1e-5f
#define NB 1024
#define NEDGE 1048576
#define EPG 1024
#define CNTF 65536.0f

__device__ __forceinline__ ushort f2bf(float f) {
  uint u = __float_as_uint(f);
  return (ushort)((u + 0x7FFFu + ((u >> 16) & 1u)) >> 16);
}

// ---------------------------------------------------------------------------
// k_prepc: conv weights cw [o][c][kk] fp32 -> bf16 cwt [o][kk*64+c].
// cwt2/cwt3 live in d_out scratch (fully overwritten by k_tail at the end).
// Grid 96 x 256 = 24576 threads, one element each.
// ---------------------------------------------------------------------------
__global__ __launch_bounds__(256) void k_prepc(
    const float* __restrict__ c2w, const float* __restrict__ c3w,
    ushort* __restrict__ cwt2, ushort* __restrict__ cwt3)
{
  const int flat = blockIdx.x * 256 + threadIdx.x;   // 0..24575
  const int m = flat >= 12288;
  const int idx = flat - (m ? 12288 : 0);
  const float* src = m ? c3w : c2w;
  ushort* dst = m ? cwt3 : cwt2;
  const int o = idx / 192, rem = idx - o * 192;
  const int kk = rem >> 6, c = rem & 63;
  dst[idx] = f2bf(src[o * 192 + c * 3 + kk]);
}

// ---------------------------------------------------------------------------
// Stage 1: EdgeConv. One block per graph. Transposed per-wave accumulators:
// aggT[wave][j][node] -> atomic bank = (w*8 + j*8 + dl) % 32, full 32-bank
// spread (was 4 banks = 16-way serialization). int4 edge loads (4/thread).
// out0 layout [node l][channel c].
// ---------------------------------------------------------------------------
__global__ __launch_bounds__(256) void k_edge(
    const float* __restrict__ x, const int* __restrict__ ei,
    const float* __restrict__ w1, const float* __restrict__ b1,
    const float* __restrict__ w2, const float* __restrict__ b2,
    float* __restrict__ out0, float* __restrict__ stats1)
{
  __shared__ float xs[64];
  __shared__ float aggT[4][5][72];   // [wave][hidden j / 4=deg][node]
  __shared__ float w1s[8], b1s[4];
  __shared__ float w2s[256], b2s[64];
  __shared__ float rs[4][64], rss[4][64];
  const int tid = threadIdx.x;
  const int b = blockIdx.x;
  const int w = tid >> 6;

  if (tid < 8) w1s[tid] = w1[tid];
  if (tid < 4) b1s[tid] = b1[tid];
  if (tid < 64) { xs[tid] = x[(b << 6) + tid]; b2s[tid] = b2[tid]; }
  w2s[tid] = w2[tid];
  for (int i = tid; i < 1440; i += 256) ((float*)aggT)[i] = 0.f;
  __syncthreads();

  const int e0 = b * EPG;
  const int4 s4 = ((const int4*)(ei + e0))[tid];
  const int4 d4 = ((const int4*)(ei + NEDGE + e0))[tid];
  float* agw = &aggT[w][0][0];
  const int sls[4] = {s4.x & 63, s4.y & 63, s4.z & 63, s4.w & 63};
  const int dls[4] = {d4.x & 63, d4.y & 63, d4.z & 63, d4.w & 63};
#pragma unroll
  for (int e = 0; e < 4; ++e) {
    const int dl = dls[e];
    const float xi = xs[dl];
    const float dx = xs[sls[e]] - xi;
#pragma unroll
    for (int j = 0; j < 4; ++j) {
      float h = fmaxf(fmaf(xi, w1s[j], fmaf(dx, w1s[4 + j], b1s[j])), 0.f);
      atomicAdd(&agw[j * 72 + dl], h);
    }
    atomicAdd(&agw[4 * 72 + dl], 1.0f);
  }
  __syncthreads();

  const int c = tid & 63, qq = tid >> 6;
  const float wc0 = w2s[c], wc1 = w2s[64 + c], wc2 = w2s[128 + c], wc3 = w2s[192 + c];
  const float b2c = b2s[c];
  float s = 0.f, ss = 0.f;
  for (int n = qq; n < 64; n += 4) {
    const float a0 = aggT[0][0][n] + aggT[1][0][n] + aggT[2][0][n] + aggT[3][0][n];
    const float a1 = aggT[0][1][n] + aggT[1][1][n] + aggT[2][1][n] + aggT[3][1][n];
    const float a2 = aggT[0][2][n] + aggT[1][2][n] + aggT[2][2][n] + aggT[3][2][n];
    const float a3v = aggT[0][3][n] + aggT[1][3][n] + aggT[2][3][n] + aggT[3][3][n];
    const float dg = aggT[0][4][n] + aggT[1][4][n] + aggT[2][4][n] + aggT[3][4][n];
    float v = a0 * wc0 + a1 * wc1 + a2 * wc2 + a3v * wc3 + dg * b2c;
    out0[(size_t)(((b << 6) + n) << 6) + c] = v;
    s += v; ss += v * v;
  }
  rs[qq][c] = s; rss[qq][c] = ss;
  __syncthreads();
  if (tid < 64) {
    atomicAdd(&stats1[tid], rs[0][tid] + rs[1][tid] + rs[2][tid] + rs[3][tid]);
    atomicAdd(&stats1[64 + tid], rss[0][tid] + rss[1][tid] + rss[2][tid] + rss[3][tid]);
  }
}

// ---------------------------------------------------------------------------
// k_convm: BN(stats_in)+ReLU -> bf16 Yt[66][72] (rows shifted +1, zero-pad
// rows 0/65), conv1d as MFMA GEMM: M=o(64), N=l(64), K=192 (kk-major,c).
// A = cwt bf16 [o][kk*64+c] staged to As[64][200]; B-frags read from
// Yt[l+kk][c-chunk] directly. Output [l][o] (+bias, pre-BN) + BN stats.
// One block per graph, 4 waves: wave w = o-tile, nt loop = l-tiles.
// ---------------------------------------------------------------------------
__global__ __launch_bounds__(256) void k_convm(
    const float* __restrict__ in,            // [1024][64 l][64 c]
    const float* __restrict__ stats_in,
    const float* __restrict__ gamma, const float* __restrict__ beta,
    const ushort* __restrict__ cwt, const float* __restrict__ cb,
    float* __restrict__ out,                 // [1024][64 l][64 o]
    float* __restrict__ stats_out)
{
  __shared__ ushort As[64][200];
  __shared__ ushort Yt[66][72];
  __shared__ float aco[64], bco[64], cbs[64];
  __shared__ float ldsS[64], ldsSS[64];
  const int tid = threadIdx.x;
  const int b = blockIdx.x;

  if (tid < 64) {
    const float sm = stats_in[tid], sq = stats_in[64 + tid];
    const float mean = sm * (1.0f / CNTF);
    const float var = sq * (1.0f / CNTF) - mean * mean;
    const float a = gamma[tid] * rsqrtf(var + EPSV);
    aco[tid] = a;
    bco[tid] = beta[tid] - mean * a;
    cbs[tid] = cb[tid];
    Yt[0][tid] = 0;
    Yt[65][tid] = 0;
  }
  __syncthreads();

  const size_t base = (size_t)b << 12;
  // stage Yt: BN+ReLU+bf16, same orientation copy ([l][c] -> row l+1)
  {
    const int lr = tid >> 4, c0 = (tid & 15) << 2;
#pragma unroll
    for (int i = 0; i < 4; ++i) {
      const int l = lr + (i << 4);
      const float4 v = *(const float4*)&in[base + (l << 6) + c0];
      const float4 a4 = *(const float4*)&aco[c0];
      const float4 b4 = *(const float4*)&bco[c0];
      *(ushort4*)&Yt[l + 1][c0] = make_ushort4(
          f2bf(fmaxf(fmaf(a4.x, v.x, b4.x), 0.f)),
          f2bf(fmaxf(fmaf(a4.y, v.y, b4.y), 0.f)),
          f2bf(fmaxf(fmaf(a4.z, v.z, b4.z), 0.f)),
          f2bf(fmaxf(fmaf(a4.w, v.w, b4.w), 0.f)));
    }
  }
  // stage As: 1536 short8
  {
    const short8* gw = (const short8*)cwt;
#pragma unroll
    for (int i = 0; i < 6; ++i) {
      const int e8 = (i << 8) + tid;
      const int o = e8 / 24, k8 = (e8 - o * 24) << 3;
      *(short8*)&As[o][k8] = gw[e8];
    }
  }
  __syncthreads();

  const int lane = tid & 63, w = tid >> 6;
  const int lm = lane & 15, q = lane >> 4;
  f32x4 acc[4];
#pragma unroll
  for (int nt = 0; nt < 4; ++nt) acc[nt] = (f32x4){0.f, 0.f, 0.f, 0.f};

#pragma unroll
  for (int kk = 0; kk < 3; ++kk) {
#pragma unroll
    for (int ks = 0; ks < 2; ++ks) {
      const short8 af = *(const short8*)&As[(w << 4) + lm][(kk << 6) + (ks << 5) + (q << 3)];
#pragma unroll
      for (int nt = 0; nt < 4; ++nt) {
        const short8 bfr = *(const short8*)&Yt[(nt << 4) + lm + kk][(ks << 5) + (q << 3)];
        acc[nt] = __builtin_amdgcn_mfma_f32_16x16x32_bf16(af, bfr, acc[nt], 0, 0, 0);
      }
    }
  }

  // epilogue: C/D col = l-tile + lm, row = o = w*16 + q*4 + i
  const int obase = (w << 4) + (q << 2);
  const float4 cb4 = *(const float4*)&cbs[obase];
  float s[4] = {0.f, 0.f, 0.f, 0.f}, ss[4] = {0.f, 0.f, 0.f, 0.f};
#pragma unroll
  for (int nt = 0; nt < 4; ++nt) {
    const int l = (nt << 4) + lm;
    float4 v = make_float4(acc[nt][0] + cb4.x, acc[nt][1] + cb4.y,
                           acc[nt][2] + cb4.z, acc[nt][3] + cb4.w);
    *(float4*)&out[base + (l << 6) + obase] = v;
    s[0] += v.x; ss[0] += v.x * v.x;
    s[1] += v.y; ss[1] += v.y * v.y;
    s[2] += v.z; ss[2] += v.z * v.z;
    s[3] += v.w; ss[3] += v.w * v.w;
  }
#pragma unroll
  for (int i = 0; i < 4; ++i) {
#pragma unroll
    for (int off = 1; off < 16; off <<= 1) {
      s[i] += __shfl_xor(s[i], off);
      ss[i] += __shfl_xor(ss[i], off);
    }
    if (lm == 0) { ldsS[obase + i] = s[i]; ldsSS[obase + i] = ss[i]; }
  }
  __syncthreads();
  if (tid < 64) {
    atomicAdd(&stats_out[tid], ldsS[tid]);
    atomicAdd(&stats_out[64 + tid], ldsSS[tid]);
  }
}

// ---------------------------------------------------------------------------
// k_prep: wm1 fp32 [4096 k][256 n] -> bf16 wbf [4096 k'][256 n] with row
// permutation k' = l*64+c <-> k = c*64+l (matches z3's [l][c] flat order).
// Grid 256 x 256.
// ---------------------------------------------------------------------------
__global__ __launch_bounds__(256) void k_prep(
    const float* __restrict__ wm1, ushort* __restrict__ wbf)
{
  const int tid = threadIdx.x;
  const int rp = (blockIdx.x << 4) + (tid >> 4);   // k' row
  const int c0 = (tid & 15) << 4;
  const int rsrc = ((rp & 63) << 6) + (rp >> 6);   // original k row
  const float* src = wm1 + ((size_t)rsrc << 8) + c0;
  ushort* dst = wbf + ((size_t)rp << 8) + c0;
#pragma unroll
  for (int i = 0; i < 4; ++i) {
    const float4 v = *(const float4*)(src + (i << 2));
    *(ushort4*)(dst + (i << 2)) = make_ushort4(f2bf(v.x), f2bf(v.y), f2bf(v.z), f2bf(v.w));
  }
}

// ---------------------------------------------------------------------------
// k_prep2: wm2,wm3 -> bf16 transposed chunk-major [kc][n][kk]; wp -> wp^T.
// (unchanged) Grid 65 x 256.
// ---------------------------------------------------------------------------
__global__ __launch_bounds__(256) void k_prep2(
    const float* __restrict__ wm2, const float* __restrict__ wm3,
    const float* __restrict__ wp,
    ushort* __restrict__ wbf2t, ushort* __restrict__ wbf3t,
    ushort* __restrict__ wptbf)
{
  const int tid = threadIdx.x;
  if (blockIdx.x == 64) {
    const int a = tid & 15, k0 = (tid >> 4) << 4;
    ushort tmp[16];
#pragma unroll
    for (int j = 0; j < 16; ++j) tmp[j] = f2bf(wp[((k0 + j) << 4) + a]);
    *(short8*)&wptbf[(a << 8) + k0] = *(short8*)&tmp[0];
    *(short8*)&wptbf[(a << 8) + k0 + 8] = *(short8*)&tmp[8];
    return;
  }
  const int base = ((blockIdx.x << 8) + tid) << 3;
  const int m = base >> 16;
  const int rem = base & 65535;
  const int kc = rem >> 14, within = rem & 16383;
  const int n = within >> 6, kk0 = within & 63;
  const float* src = m ? wm3 : wm2;
  ushort* dst = m ? wbf3t : wbf2t;
  ushort tmp[8];
#pragma unroll
  for (int j = 0; j < 8; ++j)
    tmp[j] = f2bf(src[(((kc << 6) | (kk0 + j)) << 8) + n]);
  *(short8*)&dst[rem] = *(short8*)&tmp[0];
}

// ---------------------------------------------------------------------------
// k_mlp1: h1part[bz] = (BN3+ReLU(z3)) @ wm1 partial, bf16 MFMA 16x16x32.
// z3 in [g][l][c] order (k' = l*64+c); BN channel = k'&63 -> per-element
// scale vectors. Split-K partials stored (no atomics). Grid (16,4,8).
// ---------------------------------------------------------------------------
__global__ __launch_bounds__(256) void k_mlp1(
    const float* __restrict__ z3, const float* __restrict__ stats3,
    const float* __restrict__ g3, const float* __restrict__ be3,
    const ushort* __restrict__ wbf, float* __restrict__ h1part)
{
  __shared__ ushort Ys[64][72];
  __shared__ ushort Ws[64][72];
  __shared__ float a3s[64], b3s[64];
  const int tid = threadIdx.x;
  const int bx = blockIdx.x, by = blockIdx.y, bz = blockIdx.z;

  if (tid < 64) {
    const float sm = stats3[tid], sq = stats3[64 + tid];
    const float mean = sm * (1.0f / CNTF);
    const float var = sq * (1.0f / CNTF) - mean * mean;
    const float a = g3[tid] * rsqrtf(var + EPSV);
    a3s[tid] = a;
    b3s[tid] = be3[tid] - mean * a;
  }
  __syncthreads();

  const int lane = tid & 63, w = tid >> 6;
  const int lm = lane & 15, q = lane >> 4;
  const int ry = tid >> 2, cy = (tid & 3) << 4;
  const int ngr = (tid & 15) << 2, kgr = (tid >> 4) << 2;
  const int g0 = bx << 6, n0 = by << 6;

  f32x4 acc[4];
#pragma unroll
  for (int nt = 0; nt < 4; ++nt) acc[nt] = (f32x4){0.f, 0.f, 0.f, 0.f};

  const size_t ybase = (size_t)(g0 + ry) << 12;

#pragma unroll 1
  for (int ck = 0; ck < 8; ++ck) {
    const int kc = (bz << 9) + (ck << 6);
    if (ck) __syncthreads();
#pragma unroll
    for (int i = 0; i < 4; ++i) {
      const float4 v = *(const float4*)&z3[ybase + kc + cy + (i << 2)];
      const float4 sa4 = *(const float4*)&a3s[cy + (i << 2)];
      const float4 sb4 = *(const float4*)&b3s[cy + (i << 2)];
      *(ushort4*)&Ys[ry][cy + (i << 2)] = make_ushort4(
          f2bf(fmaxf(fmaf(sa4.x, v.x, sb4.x), 0.f)),
          f2bf(fmaxf(fmaf(sa4.y, v.y, sb4.y), 0.f)),
          f2bf(fmaxf(fmaf(sa4.z, v.z, sb4.z), 0.f)),
          f2bf(fmaxf(fmaf(sa4.w, v.w, sb4.w), 0.f)));
    }
    {
      const ushort* wp0 = wbf + (((size_t)(kc + kgr)) << 8) + n0 + ngr;
      const ushort4 w0 = *(const ushort4*)(wp0);
      const ushort4 w1 = *(const ushort4*)(wp0 + 256);
      const ushort4 w2 = *(const ushort4*)(wp0 + 512);
      const ushort4 w3 = *(const ushort4*)(wp0 + 768);
      *(ushort4*)&Ws[ngr + 0][kgr] = make_ushort4(w0.x, w1.x, w2.x, w3.x);
      *(ushort4*)&Ws[ngr + 1][kgr] = make_ushort4(w0.y, w1.y, w2.y, w3.y);
      *(ushort4*)&Ws[ngr + 2][kgr] = make_ushort4(w0.z, w1.z, w2.z, w3.z);
      *(ushort4*)&Ws[ngr + 3][kgr] = make_ushort4(w0.w, w1.w, w2.w, w3.w);
    }
    __syncthreads();
#pragma unroll
    for (int ks = 0; ks < 2; ++ks) {
      const short8 af = *(const short8*)&Ys[(w << 4) + lm][(ks << 5) + (q << 3)];
#pragma unroll
      for (int nt = 0; nt < 4; ++nt) {
        const short8 bfr = *(const short8*)&Ws[(nt << 4) + lm][(ks << 5) + (q << 3)];
        acc[nt] = __builtin_amdgcn_mfma_f32_16x16x32_bf16(af, bfr, acc[nt], 0, 0, 0);
      }
    }
  }

  float* dst0 = h1part + ((size_t)bz << 18);
  const int gout = g0 + (w << 4) + (q << 2);
#pragma unroll
  for (int nt = 0; nt < 4; ++nt) {
    const int col = n0 + (nt << 4) + lm;
#pragma unroll
    for (int i = 0; i < 4; ++i)
      dst0[((size_t)(gout + i) << 8) + col] = acc[nt][i];
  }
}

// ---------------------------------------------------------------------------
// k_tail: h1 = relu(sum_bz h1part + bm1) -> h2 -> h3 -> logits -> logsoftmax.
// 64 blocks x 16 graphs. (GEMM chain unchanged from R3; h1 staging now sums
// the 8 split-K partials.)
// ---------------------------------------------------------------------------
__global__ __launch_bounds__(256) void k_tail(
    const float* __restrict__ h1part, const float* __restrict__ bm1,
    const ushort* __restrict__ wbf2t, const float* __restrict__ bm2,
    const ushort* __restrict__ wbf3t, const float* __restrict__ bm3,
    const ushort* __restrict__ wptbf, const float* __restrict__ bp,
    float* __restrict__ out)
{
  __shared__ ushort Ws[256][72];
  __shared__ ushort h1s[16][264];
  __shared__ ushort h2s[16][264];
  ushort* wpt = &Ws[0][0];
  const int tid = threadIdx.x;
  const int g0 = blockIdx.x << 4;
  const int lane = tid & 63, w = tid >> 6;
  const int lm = lane & 15, q = lane >> 4;
  const int gr = q << 2;

  // stage h1 = relu(sum of 8 partials + bm1) -> bf16
  {
    const int r = tid >> 4, c0 = (tid & 15) << 4;
    const float* srcb = h1part + ((size_t)(g0 + r) << 8) + c0;
#pragma unroll
    for (int i = 0; i < 4; ++i) {
      float4 vs = *(const float4*)(bm1 + c0 + (i << 2));
#pragma unroll
      for (int bz = 0; bz < 8; ++bz) {
        const float4 p = *(const float4*)(srcb + ((size_t)bz << 18) + (i << 2));
        vs.x += p.x; vs.y += p.y; vs.z += p.z; vs.w += p.w;
      }
      *(ushort4*)&h1s[r][c0 + (i << 2)] = make_ushort4(
          f2bf(fmaxf(vs.x, 0.f)), f2bf(fmaxf(vs.y, 0.f)),
          f2bf(fmaxf(vs.z, 0.f)), f2bf(fmaxf(vs.w, 0.f)));
    }
  }

  // ---- GEMM2
  f32x4 acc[4];
#pragma unroll
  for (int nt = 0; nt < 4; ++nt) acc[nt] = (f32x4){0.f, 0.f, 0.f, 0.f};
#pragma unroll 1
  for (int ck = 0; ck < 4; ++ck) {
    __syncthreads();
    {
      const short8* gw = (const short8*)(wbf2t + (ck << 14));
#pragma unroll
      for (int i = 0; i < 8; ++i) {
        const int e8 = (i << 8) + tid;
        const int n = e8 >> 3, kk = (e8 & 7) << 3;
        *(short8*)&Ws[n][kk] = gw[e8];
      }
    }
    __syncthreads();
#pragma unroll
    for (int ks = 0; ks < 2; ++ks) {
      const short8 af = *(const short8*)&h1s[lm][(ck << 6) + (ks << 5) + (q << 3)];
#pragma unroll
      for (int nt = 0; nt < 4; ++nt) {
        const short8 bfr = *(const short8*)&Ws[(w << 6) + (nt << 4) + lm][(ks << 5) + (q << 3)];
        acc[nt] = __builtin_amdgcn_mfma_f32_16x16x32_bf16(af, bfr, acc[nt], 0, 0, 0);
      }
    }
  }
#pragma unroll
  for (int nt = 0; nt < 4; ++nt) {
    const int col = (w << 6) + (nt << 4) + lm;
    const float bv = bm2[col];
#pragma unroll
    for (int i = 0; i < 4; ++i)
      h2s[gr + i][col] = f2bf(fmaxf(acc[nt][i] + bv, 0.f));
  }

  // ---- GEMM3
  f32x4 acc2[4];
#pragma unroll
  for (int nt = 0; nt < 4; ++nt) acc2[nt] = (f32x4){0.f, 0.f, 0.f, 0.f};
#pragma unroll 1
  for (int ck = 0; ck < 4; ++ck) {
    __syncthreads();
    {
      const short8* gw = (const short8*)(wbf3t + (ck << 14));
#pragma unroll
      for (int i = 0; i < 8; ++i) {
        const int e8 = (i << 8) + tid;
        const int n = e8 >> 3, kk = (e8 & 7) << 3;
        *(short8*)&Ws[n][kk] = gw[e8];
      }
    }
    __syncthreads();
#pragma unroll
    for (int ks = 0; ks < 2; ++ks) {
      const short8 af = *(const short8*)&h2s[lm][(ck << 6) + (ks << 5) + (q << 3)];
#pragma unroll
      for (int nt = 0; nt < 4; ++nt) {
        const short8 bfr = *(const short8*)&Ws[(w << 6) + (nt << 4) + lm][(ks << 5) + (q << 3)];
        acc2[nt] = __builtin_amdgcn_mfma_f32_16x16x32_bf16(af, bfr, acc2[nt], 0, 0, 0);
      }
    }
  }

  __syncthreads();
  {
    const short8* gw = (const short8*)wptbf;
#pragma unroll
    for (int i = 0; i < 2; ++i) {
      const int e8 = (i << 8) + tid;
      const int flat = e8 << 3;
      const int a = flat >> 8, kk = flat & 255;
      *(short8*)&wpt[a * 264 + kk] = gw[e8];
    }
  }
#pragma unroll
  for (int nt = 0; nt < 4; ++nt) {
    const int col = (w << 6) + (nt << 4) + lm;
    const float bv = bm3[col];
#pragma unroll
    for (int i = 0; i < 4; ++i)
      h2s[gr + i][col] = f2bf(fmaxf(acc2[nt][i] + bv, 0.f));
  }
  __syncthreads();

  if (w == 0) {
    f32x4 lacc = (f32x4){0.f, 0.f, 0.f, 0.f};
#pragma unroll
    for (int ks = 0; ks < 8; ++ks) {
      const short8 af = *(const short8*)&h2s[lm][(ks << 5) + (q << 3)];
      const short8 bfr = *(const short8*)&wpt[lm * 264 + (ks << 5) + (q << 3)];
      lacc = __builtin_amdgcn_mfma_f32_16x16x32_bf16(af, bfr, lacc, 0, 0, 0);
    }
    const float bpv = bp[lm];
    float lg[4], mx[4], se[4];
#pragma unroll
    for (int i = 0; i < 4; ++i) {
      lg[i] = lacc[i] + bpv;
      float m = lg[i];
#pragma unroll
      for (int off = 1; off < 16; off <<= 1) m = fmaxf(m, __shfl_xor(m, off));
      mx[i] = m;
      float e = expf(lg[i] - m);
#pragma unroll
      for (int off = 1; off < 16; off <<= 1) e += __shfl_xor(e, off);
      se[i] = e;
    }
#pragma unroll
    for (int i = 0; i < 4; ++i)
      out[((g0 + gr + i) << 4) + lm] = (lg[i] - mx[i]) - logf(se[i]);
  }
}

// ---------------------------------------------------------------------------
extern "C" void kernel_launch(void* const* d_in, const int* in_sizes, int n_in,
                              void* d_out, int out_size, void* d_ws, size_t ws_size,
                              hipStream_t stream)
{
  const float* x   = (const float*)d_in[0];
  const int*   ei  = (const int*)d_in[1];
  const float* w1  = (const float*)d_in[2];
  const float* b1  = (const float*)d_in[3];
  const float* w2  = (const float*)d_in[4];
  const float* b2  = (const float*)d_in[5];
  const float* c2w = (const float*)d_in[6];
  const float* c2b = (const float*)d_in[7];
  const float* c3w = (const float*)d_in[8];
  const float* c3b = (const float*)d_in[9];
  const float* g1  = (const float*)d_in[10];
  const float* be1 = (const float*)d_in[11];
  const float* g2  = (const float*)d_in[12];
  const float* be2 = (const float*)d_in[13];
  const float* g3  = (const float*)d_in[14];
  const float* be3 = (const float*)d_in[15];
  const float* wm1 = (const float*)d_in[16];
  const float* bm1 = (const float*)d_in[17];
  const float* wm2 = (const float*)d_in[18];
  const float* bm2 = (const float*)d_in[19];
  const float* wm3 = (const float*)d_in[20];
  const float* bm3 = (const float*)d_in[21];
  const float* wp  = (const float*)d_in[22];
  const float* bp  = (const float*)d_in[23];

  char* ws = (char*)d_ws;
  float* buf0 = (float*)ws;                        // 16 MiB: out0 -> z3
  float* buf1 = (float*)(ws + ((size_t)16 << 20)); // 16 MiB: z2 -> h1part/wbf
  float* stats = (float*)(ws + ((size_t)32 << 20));
  float* stats1 = stats;
  float* stats2 = stats + 128;
  float* stats3 = stats + 256;
  float*  h1part = buf1;                                            // 8 MiB
  ushort* wbf   = (ushort*)(ws + ((size_t)24 << 20));               // 2 MiB
  ushort* wbf2t = (ushort*)(ws + ((size_t)26 << 20));               // 128 KiB
  ushort* wbf3t = (ushort*)(ws + ((size_t)26 << 20) + (128 << 10)); // 128 KiB
  ushort* wptbf = (ushort*)(ws + ((size_t)26 << 20) + (256 << 10)); // 8 KiB
  // conv weights (48 KiB) live in d_out scratch; k_tail overwrites all of
  // d_out (64 KiB) at the end, so validation sees only k_tail's writes.
  ushort* cwt2 = (ushort*)d_out;
  ushort* cwt3 = (ushort*)d_out + 12288;

  hipMemsetAsync(stats, 0, 3 * 128 * sizeof(float), stream);
  k_prepc<<<dim3(96), dim3(256), 0, stream>>>(c2w, c3w, cwt2, cwt3);
  k_edge<<<dim3(NB), dim3(256), 0, stream>>>(x, ei, w1, b1, w2, b2, buf0, stats1);
  k_convm<<<dim3(NB), dim3(256), 0, stream>>>(buf0, stats1, g1, be1, cwt2, c2b, buf1, stats2);
  k_convm<<<dim3(NB), dim3(256), 0, stream>>>(buf1, stats2, g2, be2, cwt3, c3b, buf0, stats3);
  k_prep<<<dim3(256), dim3(256), 0, stream>>>(wm1, wbf);
  k_prep2<<<dim3(65), dim3(256), 0, stream>>>(wm2, wm3, wp, wbf2t, wbf3t, wptbf);
  k_mlp1<<<dim3(16, 4, 8), dim3(256), 0, stream>>>(buf0, stats3, g3, be3, wbf, h1part);
  k_tail<<<dim3(64), dim3(256), 0, stream>>>(h1part, bm1, wbf2t, bm2, wbf3t, bm3,
                                             wptbf, bp, (float*)d_out);
}

// Round 5
// 195.212 us; speedup vs baseline: 2.2106x; 1.2943x over previous
//
#include <hip/hip_runtime.h>
#include <cstdint>
#include <cstddef>

typedef __attribute__((ext_vector_type(8))) short short8;
typedef __attribute__((ext_vector_type(4))) float f32x4;

#define EPSV 1e-5f
#define NB 1024
#define NEDGE 1048576
#define EPG 1024
#define CNTF 65536.0f
#define REP 32           // stats replica slots (contention spreading)

__device__ __forceinline__ ushort f2bf(float f) {
  uint u = __float_as_uint(f);
  return (ushort)((u + 0x7FFFu + ((u >> 16) & 1u)) >> 16);
}

// ---------------------------------------------------------------------------
// k_prepc: conv weights cw [o][c][kk] fp32 -> bf16 cwt [o][kk*64+c].
// cwt2/cwt3 live in d_out scratch (fully overwritten by k_tail at the end).
// ---------------------------------------------------------------------------
__global__ __launch_bounds__(256) void k_prepc(
    const float* __restrict__ c2w, const float* __restrict__ c3w,
    ushort* __restrict__ cwt2, ushort* __restrict__ cwt3)
{
  const int flat = blockIdx.x * 256 + threadIdx.x;   // 0..24575
  const int m = flat >= 12288;
  const int idx = flat - (m ? 12288 : 0);
  const float* src = m ? c3w : c2w;
  ushort* dst = m ? cwt3 : cwt2;
  const int o = idx / 192, rem = idx - o * 192;
  const int kk = rem >> 6, c = rem & 63;
  dst[idx] = f2bf(src[o * 192 + c * 3 + kk]);
}

// ---------------------------------------------------------------------------
// Stage 1: EdgeConv. One block per graph. Per-wave LDS accumulators, then
// one combine pass -> aggC[64][8], float4 epilogue reads. BN1 stats go to
// replica slot (b & 31) to break global-atomic same-address serialization.
// out0 layout [node l][channel c].
// ---------------------------------------------------------------------------
__global__ __launch_bounds__(256) void k_edge(
    const float* __restrict__ x, const int* __restrict__ ei,
    const float* __restrict__ w1, const float* __restrict__ b1,
    const float* __restrict__ w2, const float* __restrict__ b2,
    float* __restrict__ out0, float* __restrict__ stats1)
{
  __shared__ float xs[64];
  __shared__ float aggT[4][5][72];   // [wave][hidden j / 4=deg][node]
  __shared__ float aggC[64][8];      // combined: [node][j0..3, deg]
  __shared__ float w1s[8], b1s[4];
  __shared__ float w2s[256], b2s[64];
  __shared__ float rs[4][64], rss[4][64];
  const int tid = threadIdx.x;
  const int b = blockIdx.x;
  const int w = tid >> 6;

  if (tid < 8) w1s[tid] = w1[tid];
  if (tid < 4) b1s[tid] = b1[tid];
  if (tid < 64) { xs[tid] = x[(b << 6) + tid]; b2s[tid] = b2[tid]; }
  w2s[tid] = w2[tid];
  for (int i = tid; i < 1440; i += 256) ((float*)aggT)[i] = 0.f;
  __syncthreads();

  const int e0 = b * EPG;
  const int4 s4 = ((const int4*)(ei + e0))[tid];
  const int4 d4 = ((const int4*)(ei + NEDGE + e0))[tid];
  float* agw = &aggT[w][0][0];
  const int sls[4] = {s4.x & 63, s4.y & 63, s4.z & 63, s4.w & 63};
  const int dls[4] = {d4.x & 63, d4.y & 63, d4.z & 63, d4.w & 63};
#pragma unroll
  for (int e = 0; e < 4; ++e) {
    const int dl = dls[e];
    const float xi = xs[dl];
    const float dx = xs[sls[e]] - xi;
#pragma unroll
    for (int j = 0; j < 4; ++j) {
      float h = fmaxf(fmaf(xi, w1s[j], fmaf(dx, w1s[4 + j], b1s[j])), 0.f);
      atomicAdd(&agw[j * 72 + dl], h);
    }
    atomicAdd(&agw[4 * 72 + dl], 1.0f);
  }
  __syncthreads();

  // combine 4 wave-copies (lane = node, stride-1 conflict-free reads)
  if (tid < 64) {
    const int n = tid;
    const float a0 = aggT[0][0][n] + aggT[1][0][n] + aggT[2][0][n] + aggT[3][0][n];
    const float a1 = aggT[0][1][n] + aggT[1][1][n] + aggT[2][1][n] + aggT[3][1][n];
    const float a2 = aggT[0][2][n] + aggT[1][2][n] + aggT[2][2][n] + aggT[3][2][n];
    const float a3v = aggT[0][3][n] + aggT[1][3][n] + aggT[2][3][n] + aggT[3][3][n];
    const float dg = aggT[0][4][n] + aggT[1][4][n] + aggT[2][4][n] + aggT[3][4][n];
    *(float4*)&aggC[n][0] = make_float4(a0, a1, a2, a3v);
    aggC[n][4] = dg;
  }
  __syncthreads();

  const int c = tid & 63, qq = tid >> 6;
  const float wc0 = w2s[c], wc1 = w2s[64 + c], wc2 = w2s[128 + c], wc3 = w2s[192 + c];
  const float b2c = b2s[c];
  float s = 0.f, ss = 0.f;
  for (int n = qq; n < 64; n += 4) {
    const float4 a = *(const float4*)&aggC[n][0];   // broadcast
    const float dg = aggC[n][4];
    float v = a.x * wc0 + a.y * wc1 + a.z * wc2 + a.w * wc3 + dg * b2c;
    out0[(size_t)(((b << 6) + n) << 6) + c] = v;
    s += v; ss += v * v;
  }
  rs[qq][c] = s; rss[qq][c] = ss;
  __syncthreads();
  if (tid < 64) {
    float* dst = stats1 + ((b & (REP - 1)) << 7);
    atomicAdd(&dst[tid], rs[0][tid] + rs[1][tid] + rs[2][tid] + rs[3][tid]);
    atomicAdd(&dst[64 + tid], rss[0][tid] + rss[1][tid] + rss[2][tid] + rss[3][tid]);
  }
}

// ---------------------------------------------------------------------------
// k_convm: BN(sum of stats_in replicas)+ReLU -> bf16 Yt, conv1d as MFMA
// GEMM (M=o, N=l, K=192). Output [l][o] + replica BN stats.
// ---------------------------------------------------------------------------
__global__ __launch_bounds__(256) void k_convm(
    const float* __restrict__ in,            // [1024][64 l][64 c]
    const float* __restrict__ stats_in,      // [REP][128]
    const float* __restrict__ gamma, const float* __restrict__ beta,
    const ushort* __restrict__ cwt, const float* __restrict__ cb,
    float* __restrict__ out,                 // [1024][64 l][64 o]
    float* __restrict__ stats_out)           // [REP][128]
{
  __shared__ ushort As[64][200];
  __shared__ ushort Yt[66][72];
  __shared__ float aco[64], bco[64], cbs[64];
  __shared__ float ldsS[64], ldsSS[64];
  const int tid = threadIdx.x;
  const int b = blockIdx.x;

  if (tid < 64) {
    float sm = 0.f, sq = 0.f;
#pragma unroll 8
    for (int r = 0; r < REP; ++r) {
      sm += stats_in[(r << 7) + tid];
      sq += stats_in[(r << 7) + 64 + tid];
    }
    const float mean = sm * (1.0f / CNTF);
    const float var = sq * (1.0f / CNTF) - mean * mean;
    const float a = gamma[tid] * rsqrtf(var + EPSV);
    aco[tid] = a;
    bco[tid] = beta[tid] - mean * a;
    cbs[tid] = cb[tid];
    Yt[0][tid] = 0;
    Yt[65][tid] = 0;
  }
  __syncthreads();

  const size_t base = (size_t)b << 12;
  {
    const int lr = tid >> 4, c0 = (tid & 15) << 2;
#pragma unroll
    for (int i = 0; i < 4; ++i) {
      const int l = lr + (i << 4);
      const float4 v = *(const float4*)&in[base + (l << 6) + c0];
      const float4 a4 = *(const float4*)&aco[c0];
      const float4 b4 = *(const float4*)&bco[c0];
      *(ushort4*)&Yt[l + 1][c0] = make_ushort4(
          f2bf(fmaxf(fmaf(a4.x, v.x, b4.x), 0.f)),
          f2bf(fmaxf(fmaf(a4.y, v.y, b4.y), 0.f)),
          f2bf(fmaxf(fmaf(a4.z, v.z, b4.z), 0.f)),
          f2bf(fmaxf(fmaf(a4.w, v.w, b4.w), 0.f)));
    }
  }
  {
    const short8* gw = (const short8*)cwt;
#pragma unroll
    for (int i = 0; i < 6; ++i) {
      const int e8 = (i << 8) + tid;
      const int o = e8 / 24, k8 = (e8 - o * 24) << 3;
      *(short8*)&As[o][k8] = gw[e8];
    }
  }
  __syncthreads();

  const int lane = tid & 63, w = tid >> 6;
  const int lm = lane & 15, q = lane >> 4;
  f32x4 acc[4];
#pragma unroll
  for (int nt = 0; nt < 4; ++nt) acc[nt] = (f32x4){0.f, 0.f, 0.f, 0.f};

#pragma unroll
  for (int kk = 0; kk < 3; ++kk) {
#pragma unroll
    for (int ks = 0; ks < 2; ++ks) {
      const short8 af = *(const short8*)&As[(w << 4) + lm][(kk << 6) + (ks << 5) + (q << 3)];
#pragma unroll
      for (int nt = 0; nt < 4; ++nt) {
        const short8 bfr = *(const short8*)&Yt[(nt << 4) + lm + kk][(ks << 5) + (q << 3)];
        acc[nt] = __builtin_amdgcn_mfma_f32_16x16x32_bf16(af, bfr, acc[nt], 0, 0, 0);
      }
    }
  }

  const int obase = (w << 4) + (q << 2);
  const float4 cb4 = *(const float4*)&cbs[obase];
  float s[4] = {0.f, 0.f, 0.f, 0.f}, ss[4] = {0.f, 0.f, 0.f, 0.f};
#pragma unroll
  for (int nt = 0; nt < 4; ++nt) {
    const int l = (nt << 4) + lm;
    float4 v = make_float4(acc[nt][0] + cb4.x, acc[nt][1] + cb4.y,
                           acc[nt][2] + cb4.z, acc[nt][3] + cb4.w);
    *(float4*)&out[base + (l << 6) + obase] = v;
    s[0] += v.x; ss[0] += v.x * v.x;
    s[1] += v.y; ss[1] += v.y * v.y;
    s[2] += v.z; ss[2] += v.z * v.z;
    s[3] += v.w; ss[3] += v.w * v.w;
  }
#pragma unroll
  for (int i = 0; i < 4; ++i) {
#pragma unroll
    for (int off = 1; off < 16; off <<= 1) {
      s[i] += __shfl_xor(s[i], off);
      ss[i] += __shfl_xor(ss[i], off);
    }
    if (lm == 0) { ldsS[obase + i] = s[i]; ldsSS[obase + i] = ss[i]; }
  }
  __syncthreads();
  if (tid < 64) {
    float* dst = stats_out + ((b & (REP - 1)) << 7);
    atomicAdd(&dst[tid], ldsS[tid]);
    atomicAdd(&dst[64 + tid], ldsSS[tid]);
  }
}

// ---------------------------------------------------------------------------
// k_prep: wm1 fp32 [4096 k][256 n] -> bf16 wbf [4096 k'][256 n], row perm
// k' = l*64+c <-> k = c*64+l (matches z3's [l][c] flat order).
// ---------------------------------------------------------------------------
__global__ __launch_bounds__(256) void k_prep(
    const float* __restrict__ wm1, ushort* __restrict__ wbf)
{
  const int tid = threadIdx.x;
  const int rp = (blockIdx.x << 4) + (tid >> 4);   // k' row
  const int c0 = (tid & 15) << 4;
  const int rsrc = ((rp & 63) << 6) + (rp >> 6);   // original k row
  const float* src = wm1 + ((size_t)rsrc << 8) + c0;
  ushort* dst = wbf + ((size_t)rp << 8) + c0;
#pragma unroll
  for (int i = 0; i < 4; ++i) {
    const float4 v = *(const float4*)(src + (i << 2));
    *(ushort4*)(dst + (i << 2)) = make_ushort4(f2bf(v.x), f2bf(v.y), f2bf(v.z), f2bf(v.w));
  }
}

// ---------------------------------------------------------------------------
// k_prep2: wm2,wm3 -> bf16 transposed chunk-major [kc][n][kk]; wp -> wp^T.
// ---------------------------------------------------------------------------
__global__ __launch_bounds__(256) void k_prep2(
    const float* __restrict__ wm2, const float* __restrict__ wm3,
    const float* __restrict__ wp,
    ushort* __restrict__ wbf2t, ushort* __restrict__ wbf3t,
    ushort* __restrict__ wptbf)
{
  const int tid = threadIdx.x;
  if (blockIdx.x == 64) {
    const int a = tid & 15, k0 = (tid >> 4) << 4;
    ushort tmp[16];
#pragma unroll
    for (int j = 0; j < 16; ++j) tmp[j] = f2bf(wp[((k0 + j) << 4) + a]);
    *(short8*)&wptbf[(a << 8) + k0] = *(short8*)&tmp[0];
    *(short8*)&wptbf[(a << 8) + k0 + 8] = *(short8*)&tmp[8];
    return;
  }
  const int base = ((blockIdx.x << 8) + tid) << 3;
  const int m = base >> 16;
  const int rem = base & 65535;
  const int kc = rem >> 14, within = rem & 16383;
  const int n = within >> 6, kk0 = within & 63;
  const float* src = m ? wm3 : wm2;
  ushort* dst = m ? wbf3t : wbf2t;
  ushort tmp[8];
#pragma unroll
  for (int j = 0; j < 8; ++j)
    tmp[j] = f2bf(src[(((kc << 6) | (kk0 + j)) << 8) + n]);
  *(short8*)&dst[rem] = *(short8*)&tmp[0];
}

// ---------------------------------------------------------------------------
// k_mlp1: h1part[bz] = (BN3+ReLU(z3)) @ wm1 partial, bf16 MFMA 16x16x32.
// Split-K partials stored (no atomics). Grid (16,4,8).
// ---------------------------------------------------------------------------
__global__ __launch_bounds__(256) void k_mlp1(
    const float* __restrict__ z3, const float* __restrict__ stats3,
    const float* __restrict__ g3, const float* __restrict__ be3,
    const ushort* __restrict__ wbf, float* __restrict__ h1part)
{
  __shared__ ushort Ys[64][72];
  __shared__ ushort Ws[64][72];
  __shared__ float a3s[64], b3s[64];
  const int tid = threadIdx.x;
  const int bx = blockIdx.x, by = blockIdx.y, bz = blockIdx.z;

  if (tid < 64) {
    float sm = 0.f, sq = 0.f;
#pragma unroll 8
    for (int r = 0; r < REP; ++r) {
      sm += stats3[(r << 7) + tid];
      sq += stats3[(r << 7) + 64 + tid];
    }
    const float mean = sm * (1.0f / CNTF);
    const float var = sq * (1.0f / CNTF) - mean * mean;
    const float a = g3[tid] * rsqrtf(var + EPSV);
    a3s[tid] = a;
    b3s[tid] = be3[tid] - mean * a;
  }
  __syncthreads();

  const int lane = tid & 63, w = tid >> 6;
  const int lm = lane & 15, q = lane >> 4;
  const int ry = tid >> 2, cy = (tid & 3) << 4;
  const int ngr = (tid & 15) << 2, kgr = (tid >> 4) << 2;
  const int g0 = bx << 6, n0 = by << 6;

  f32x4 acc[4];
#pragma unroll
  for (int nt = 0; nt < 4; ++nt) acc[nt] = (f32x4){0.f, 0.f, 0.f, 0.f};

  const size_t ybase = (size_t)(g0 + ry) << 12;

#pragma unroll 1
  for (int ck = 0; ck < 8; ++ck) {
    const int kc = (bz << 9) + (ck << 6);
    if (ck) __syncthreads();
#pragma unroll
    for (int i = 0; i < 4; ++i) {
      const float4 v = *(const float4*)&z3[ybase + kc + cy + (i << 2)];
      const float4 sa4 = *(const float4*)&a3s[cy + (i << 2)];
      const float4 sb4 = *(const float4*)&b3s[cy + (i << 2)];
      *(ushort4*)&Ys[ry][cy + (i << 2)] = make_ushort4(
          f2bf(fmaxf(fmaf(sa4.x, v.x, sb4.x), 0.f)),
          f2bf(fmaxf(fmaf(sa4.y, v.y, sb4.y), 0.f)),
          f2bf(fmaxf(fmaf(sa4.z, v.z, sb4.z), 0.f)),
          f2bf(fmaxf(fmaf(sa4.w, v.w, sb4.w), 0.f)));
    }
    {
      const ushort* wp0 = wbf + (((size_t)(kc + kgr)) << 8) + n0 + ngr;
      const ushort4 w0 = *(const ushort4*)(wp0);
      const ushort4 w1 = *(const ushort4*)(wp0 + 256);
      const ushort4 w2 = *(const ushort4*)(wp0 + 512);
      const ushort4 w3 = *(const ushort4*)(wp0 + 768);
      *(ushort4*)&Ws[ngr + 0][kgr] = make_ushort4(w0.x, w1.x, w2.x, w3.x);
      *(ushort4*)&Ws[ngr + 1][kgr] = make_ushort4(w0.y, w1.y, w2.y, w3.y);
      *(ushort4*)&Ws[ngr + 2][kgr] = make_ushort4(w0.z, w1.z, w2.z, w3.z);
      *(ushort4*)&Ws[ngr + 3][kgr] = make_ushort4(w0.w, w1.w, w2.w, w3.w);
    }
    __syncthreads();
#pragma unroll
    for (int ks = 0; ks < 2; ++ks) {
      const short8 af = *(const short8*)&Ys[(w << 4) + lm][(ks << 5) + (q << 3)];
#pragma unroll
      for (int nt = 0; nt < 4; ++nt) {
        const short8 bfr = *(const short8*)&Ws[(nt << 4) + lm][(ks << 5) + (q << 3)];
        acc[nt] = __builtin_amdgcn_mfma_f32_16x16x32_bf16(af, bfr, acc[nt], 0, 0, 0);
      }
    }
  }

  float* dst0 = h1part + ((size_t)bz << 18);
  const int gout = g0 + (w << 4) + (q << 2);
#pragma unroll
  for (int nt = 0; nt < 4; ++nt) {
    const int col = n0 + (nt << 4) + lm;
#pragma unroll
    for (int i = 0; i < 4; ++i)
      dst0[((size_t)(gout + i) << 8) + col] = acc[nt][i];
  }
}

// ---------------------------------------------------------------------------
// k_tail: h1 = relu(sum_bz h1part + bm1) -> h2 -> h3 -> logits -> logsoftmax.
// 64 blocks x 16 graphs.
// ---------------------------------------------------------------------------
__global__ __launch_bounds__(256) void k_tail(
    const float* __restrict__ h1part, const float* __restrict__ bm1,
    const ushort* __restrict__ wbf2t, const float* __restrict__ bm2,
    const ushort* __restrict__ wbf3t, const float* __restrict__ bm3,
    const ushort* __restrict__ wptbf, const float* __restrict__ bp,
    float* __restrict__ out)
{
  __shared__ ushort Ws[256][72];
  __shared__ ushort h1s[16][264];
  __shared__ ushort h2s[16][264];
  ushort* wpt = &Ws[0][0];
  const int tid = threadIdx.x;
  const int g0 = blockIdx.x << 4;
  const int lane = tid & 63, w = tid >> 6;
  const int lm = lane & 15, q = lane >> 4;
  const int gr = q << 2;

  {
    const int r = tid >> 4, c0 = (tid & 15) << 4;
    const float* srcb = h1part + ((size_t)(g0 + r) << 8) + c0;
#pragma unroll
    for (int i = 0; i < 4; ++i) {
      float4 vs = *(const float4*)(bm1 + c0 + (i << 2));
#pragma unroll
      for (int bz = 0; bz < 8; ++bz) {
        const float4 p = *(const float4*)(srcb + ((size_t)bz << 18) + (i << 2));
        vs.x += p.x; vs.y += p.y; vs.z += p.z; vs.w += p.w;
      }
      *(ushort4*)&h1s[r][c0 + (i << 2)] = make_ushort4(
          f2bf(fmaxf(vs.x, 0.f)), f2bf(fmaxf(vs.y, 0.f)),
          f2bf(fmaxf(vs.z, 0.f)), f2bf(fmaxf(vs.w, 0.f)));
    }
  }

  // ---- GEMM2
  f32x4 acc[4];
#pragma unroll
  for (int nt = 0; nt < 4; ++nt) acc[nt] = (f32x4){0.f, 0.f, 0.f, 0.f};
#pragma unroll 1
  for (int ck = 0; ck < 4; ++ck) {
    __syncthreads();
    {
      const short8* gw = (const short8*)(wbf2t + (ck << 14));
#pragma unroll
      for (int i = 0; i < 8; ++i) {
        const int e8 = (i << 8) + tid;
        const int n = e8 >> 3, kk = (e8 & 7) << 3;
        *(short8*)&Ws[n][kk] = gw[e8];
      }
    }
    __syncthreads();
#pragma unroll
    for (int ks = 0; ks < 2; ++ks) {
      const short8 af = *(const short8*)&h1s[lm][(ck << 6) + (ks << 5) + (q << 3)];
#pragma unroll
      for (int nt = 0; nt < 4; ++nt) {
        const short8 bfr = *(const short8*)&Ws[(w << 6) + (nt << 4) + lm][(ks << 5) + (q << 3)];
        acc[nt] = __builtin_amdgcn_mfma_f32_16x16x32_bf16(af, bfr, acc[nt], 0, 0, 0);
      }
    }
  }
#pragma unroll
  for (int nt = 0; nt < 4; ++nt) {
    const int col = (w << 6) + (nt << 4) + lm;
    const float bv = bm2[col];
#pragma unroll
    for (int i = 0; i < 4; ++i)
      h2s[gr + i][col] = f2bf(fmaxf(acc[nt][i] + bv, 0.f));
  }

  // ---- GEMM3
  f32x4 acc2[4];
#pragma unroll
  for (int nt = 0; nt < 4; ++nt) acc2[nt] = (f32x4){0.f, 0.f, 0.f, 0.f};
#pragma unroll 1
  for (int ck = 0; ck < 4; ++ck) {
    __syncthreads();
    {
      const short8* gw = (const short8*)(wbf3t + (ck << 14));
#pragma unroll
      for (int i = 0; i < 8; ++i) {
        const int e8 = (i << 8) + tid;
        const int n = e8 >> 3, kk = (e8 & 7) << 3;
        *(short8*)&Ws[n][kk] = gw[e8];
      }
    }
    __syncthreads();
#pragma unroll
    for (int ks = 0; ks < 2; ++ks) {
      const short8 af = *(const short8*)&h2s[lm][(ck << 6) + (ks << 5) + (q << 3)];
#pragma unroll
      for (int nt = 0; nt < 4; ++nt) {
        const short8 bfr = *(const short8*)&Ws[(w << 6) + (nt << 4) + lm][(ks << 5) + (q << 3)];
        acc2[nt] = __builtin_amdgcn_mfma_f32_16x16x32_bf16(af, bfr, acc2[nt], 0, 0, 0);
      }
    }
  }

  __syncthreads();
  {
    const short8* gw = (const short8*)wptbf;
#pragma unroll
    for (int i = 0; i < 2; ++i) {
      const int e8 = (i << 8) + tid;
      const int flat = e8 << 3;
      const int a = flat >> 8, kk = flat & 255;
      *(short8*)&wpt[a * 264 + kk] = gw[e8];
    }
  }
#pragma unroll
  for (int nt = 0; nt < 4; ++nt) {
    const int col = (w << 6) + (nt << 4) + lm;
    const float bv = bm3[col];
#pragma unroll
    for (int i = 0; i < 4; ++i)
      h2s[gr + i][col] = f2bf(fmaxf(acc2[nt][i] + bv, 0.f));
  }
  __syncthreads();

  if (w == 0) {
    f32x4 lacc = (f32x4){0.f, 0.f, 0.f, 0.f};
#pragma unroll
    for (int ks = 0; ks < 8; ++ks) {
      const short8 af = *(const short8*)&h2s[lm][(ks << 5) + (q << 3)];
      const short8 bfr = *(const short8*)&wpt[lm * 264 + (ks << 5) + (q << 3)];
      lacc = __builtin_amdgcn_mfma_f32_16x16x32_bf16(af, bfr, lacc, 0, 0, 0);
    }
    const float bpv = bp[lm];
    float lg[4], mx[4], se[4];
#pragma unroll
    for (int i = 0; i < 4; ++i) {
      lg[i] = lacc[i] + bpv;
      float m = lg[i];
#pragma unroll
      for (int off = 1; off < 16; off <<= 1) m = fmaxf(m, __shfl_xor(m, off));
      mx[i] = m;
      float e = expf(lg[i] - m);
#pragma unroll
      for (int off = 1; off < 16; off <<= 1) e += __shfl_xor(e, off);
      se[i] = e;
    }
#pragma unroll
    for (int i = 0; i < 4; ++i)
      out[((g0 + gr + i) << 4) + lm] = (lg[i] - mx[i]) - logf(se[i]);
  }
}

// ---------------------------------------------------------------------------
extern "C" void kernel_launch(void* const* d_in, const int* in_sizes, int n_in,
                              void* d_out, int out_size, void* d_ws, size_t ws_size,
                              hipStream_t stream)
{
  const float* x   = (const float*)d_in[0];
  const int*   ei  = (const int*)d_in[1];
  const float* w1  = (const float*)d_in[2];
  const float* b1  = (const float*)d_in[3];
  const float* w2  = (const float*)d_in[4];
  const float* b2  = (const float*)d_in[5];
  const float* c2w = (const float*)d_in[6];
  const float* c2b = (const float*)d_in[7];
  const float* c3w = (const float*)d_in[8];
  const float* c3b = (const float*)d_in[9];
  const float* g1  = (const float*)d_in[10];
  const float* be1 = (const float*)d_in[11];
  const float* g2  = (const float*)d_in[12];
  const float* be2 = (const float*)d_in[13];
  const float* g3  = (const float*)d_in[14];
  const float* be3 = (const float*)d_in[15];
  const float* wm1 = (const float*)d_in[16];
  const float* bm1 = (const float*)d_in[17];
  const float* wm2 = (const float*)d_in[18];
  const float* bm2 = (const float*)d_in[19];
  const float* wm3 = (const float*)d_in[20];
  const float* bm3 = (const float*)d_in[21];
  const float* wp  = (const float*)d_in[22];
  const float* bp  = (const float*)d_in[23];

  char* ws = (char*)d_ws;
  float* buf0 = (float*)ws;                        // 16 MiB: out0 -> z3
  float* buf1 = (float*)(ws + ((size_t)16 << 20)); // 16 MiB: z2 -> h1part
  float* stats = (float*)(ws + ((size_t)32 << 20));
  float* stats1 = stats;                  // [REP][128]
  float* stats2 = stats + REP * 128;
  float* stats3 = stats + 2 * REP * 128;
  float*  h1part = buf1;                                            // 8 MiB
  ushort* wbf   = (ushort*)(ws + ((size_t)24 << 20));               // 2 MiB
  ushort* wbf2t = (ushort*)(ws + ((size_t)26 << 20));               // 128 KiB
  ushort* wbf3t = (ushort*)(ws + ((size_t)26 << 20) + (128 << 10)); // 128 KiB
  ushort* wptbf = (ushort*)(ws + ((size_t)26 << 20) + (256 << 10)); // 8 KiB
  ushort* cwt2 = (ushort*)d_out;          // d_out scratch, overwritten by k_tail
  ushort* cwt3 = (ushort*)d_out + 12288;

  hipMemsetAsync(stats, 0, 3 * REP * 128 * sizeof(float), stream);
  k_prepc<<<dim3(96), dim3(256), 0, stream>>>(c2w, c3w, cwt2, cwt3);
  k_edge<<<dim3(NB), dim3(256), 0, stream>>>(x, ei, w1, b1, w2, b2, buf0, stats1);
  k_convm<<<dim3(NB), dim3(256), 0, stream>>>(buf0, stats1, g1, be1, cwt2, c2b, buf1, stats2);
  k_convm<<<dim3(NB), dim3(256), 0, stream>>>(buf1, stats2, g2, be2, cwt3, c3b, buf0, stats3);
  k_prep<<<dim3(256), dim3(256), 0, stream>>>(wm1, wbf);
  k_prep2<<<dim3(65), dim3(256), 0, stream>>>(wm2, wm3, wp, wbf2t, wbf3t, wptbf);
  k_mlp1<<<dim3(16, 4, 8), dim3(256), 0, stream>>>(buf0, stats3, g3, be3, wbf, h1part);
  k_tail<<<dim3(64), dim3(256), 0, stream>>>(h1part, bm1, wbf2t, bm2, wbf3t, bm3,
                                             wptbf, bp, (float*)d_out);
}

// Round 6
// 187.823 us; speedup vs baseline: 2.2976x; 1.0393x over previous
//
#include <hip/hip_runtime.h>
#include <cstdint>
#include <cstddef>

typedef __attribute__((ext_vector_type(8))) short short8;
typedef __attribute__((ext_vector_type(8))) unsigned short ushort8;
typedef __attribute__((ext_vector_type(4))) float f32x4;

#define EPSV 1e-5f
#define NB 1024
#define NEDGE 1048576
#define EPG 1024
#define CNTF 65536.0f
#define REP 32           // stats replica slots (contention spreading)

__device__ __forceinline__ ushort f2bf(float f) {
  uint u = __float_as_uint(f);
  return (ushort)((u + 0x7FFFu + ((u >> 16) & 1u)) >> 16);
}
__device__ __forceinline__ float bf2f(ushort u) {
  return __uint_as_float((uint)u << 16);
}

// ---------------------------------------------------------------------------
// k_prepw: all weight preprocessing + stats zeroing in ONE kernel.
//  blocks 0..255   : wm1 -> wbf1t bf16 chunk-major [kc][n][kk], where the
//                    represented k' = kc*64+kk maps to source row kk*64+kc
//                    (row-perm matching z3's [l][c] flat order).
//  blocks 256..319 : wm2,wm3 -> wbf2t/wbf3t bf16 chunk-major [kc][n][kk].
//  block  320      : wp -> wpt bf16 [a][k].
//  blocks 321..416 : conv weights [o][c][kk] -> bf16 cwt [o][kk*64+c].
//  block  417      : zero stats (3*REP*128 floats).
// ---------------------------------------------------------------------------
__global__ __launch_bounds__(256) void k_prepw(
    const float* __restrict__ wm1, const float* __restrict__ wm2,
    const float* __restrict__ wm3, const float* __restrict__ wp,
    const float* __restrict__ c2w, const float* __restrict__ c3w,
    ushort* __restrict__ wbf1t, ushort* __restrict__ wbf2t,
    ushort* __restrict__ wbf3t, ushort* __restrict__ wptbf,
    ushort* __restrict__ cwt2, ushort* __restrict__ cwt3,
    float* __restrict__ stats)
{
  __shared__ ushort T[64][72];
  const int tid = threadIdx.x;
  const int bb = blockIdx.x;

  if (bb < 256) {
    const int kc = bb >> 2, n0 = (bb & 3) << 6;
    const int kk = tid >> 2, np = (tid & 3) << 4;
    const float* srow = wm1 + (((size_t)(kk << 6) + kc) << 8) + n0 + np;
#pragma unroll
    for (int i = 0; i < 4; ++i) {
      const float4 v = *(const float4*)(srow + (i << 2));
      const int n = np + (i << 2);
      T[n + 0][kk] = f2bf(v.x); T[n + 1][kk] = f2bf(v.y);
      T[n + 2][kk] = f2bf(v.z); T[n + 3][kk] = f2bf(v.w);
    }
    __syncthreads();
    ushort* dst = wbf1t + ((size_t)kc << 14) + (n0 << 6);
    const int nl = tid >> 2, qk = (tid & 3) << 4;
    *(ushort8*)(dst + (nl << 6) + qk) = *(ushort8*)&T[nl][qk];
    *(ushort8*)(dst + (nl << 6) + qk + 8) = *(ushort8*)&T[nl][qk + 8];
    return;
  }
  if (bb < 320) {
    const int base = (((bb - 256) << 8) + tid) << 3;
    const int m = base >> 16;
    const int rem = base & 65535;
    const int kc = rem >> 14, within = rem & 16383;
    const int n = within >> 6, kk0 = within & 63;
    const float* src = m ? wm3 : wm2;
    ushort* dst = m ? wbf3t : wbf2t;
    ushort tmp[8];
#pragma unroll
    for (int j = 0; j < 8; ++j)
      tmp[j] = f2bf(src[(((kc << 6) | (kk0 + j)) << 8) + n]);
    *(ushort8*)&dst[rem] = *(ushort8*)&tmp[0];
    return;
  }
  if (bb == 320) {
    const int a = tid & 15, k0 = (tid >> 4) << 4;
    ushort tmp[16];
#pragma unroll
    for (int j = 0; j < 16; ++j) tmp[j] = f2bf(wp[((k0 + j) << 4) + a]);
    *(ushort8*)&wptbf[(a << 8) + k0] = *(ushort8*)&tmp[0];
    *(ushort8*)&wptbf[(a << 8) + k0 + 8] = *(ushort8*)&tmp[8];
    return;
  }
  if (bb == 417) {
    float4 z4 = make_float4(0.f, 0.f, 0.f, 0.f);
#pragma unroll
    for (int i = 0; i < 12; ++i) ((float4*)stats)[(i << 8) + tid] = z4;
    return;
  }
  const int flat = (bb - 321) * 256 + tid;   // 0..24575
  const int m = flat >= 12288;
  const int idx = flat - (m ? 12288 : 0);
  const float* src = m ? c3w : c2w;
  ushort* dst = m ? cwt3 : cwt2;
  const int o = idx / 192, rem = idx - o * 192;
  const int kk = rem >> 6, c = rem & 63;
  dst[idx] = f2bf(src[o * 192 + c * 3 + kk]);
}

// ---------------------------------------------------------------------------
// Stage 1: EdgeConv. One block per graph; per-wave LDS accumulators; out0
// written bf16 (pre-BN1). BN1 stats fp32, replica slot (b&31).
// out0 layout [node l][channel c], bf16.
// ---------------------------------------------------------------------------
__global__ __launch_bounds__(256) void k_edge(
    const float* __restrict__ x, const int* __restrict__ ei,
    const float* __restrict__ w1, const float* __restrict__ b1,
    const float* __restrict__ w2, const float* __restrict__ b2,
    ushort* __restrict__ out0, float* __restrict__ stats1)
{
  __shared__ float xs[64];
  __shared__ float aggT[4][5][72];
  __shared__ float aggC[64][8];
  __shared__ float w1s[8], b1s[4];
  __shared__ float w2s[256], b2s[64];
  __shared__ float rs[4][64], rss[4][64];
  const int tid = threadIdx.x;
  const int b = blockIdx.x;
  const int w = tid >> 6;

  if (tid < 8) w1s[tid] = w1[tid];
  if (tid < 4) b1s[tid] = b1[tid];
  if (tid < 64) { xs[tid] = x[(b << 6) + tid]; b2s[tid] = b2[tid]; }
  w2s[tid] = w2[tid];
  for (int i = tid; i < 1440; i += 256) ((float*)aggT)[i] = 0.f;
  __syncthreads();

  const int e0 = b * EPG;
  const int4 s4 = ((const int4*)(ei + e0))[tid];
  const int4 d4 = ((const int4*)(ei + NEDGE + e0))[tid];
  float* agw = &aggT[w][0][0];
  const int sls[4] = {s4.x & 63, s4.y & 63, s4.z & 63, s4.w & 63};
  const int dls[4] = {d4.x & 63, d4.y & 63, d4.z & 63, d4.w & 63};
#pragma unroll
  for (int e = 0; e < 4; ++e) {
    const int dl = dls[e];
    const float xi = xs[dl];
    const float dx = xs[sls[e]] - xi;
#pragma unroll
    for (int j = 0; j < 4; ++j) {
      float h = fmaxf(fmaf(xi, w1s[j], fmaf(dx, w1s[4 + j], b1s[j])), 0.f);
      atomicAdd(&agw[j * 72 + dl], h);
    }
    atomicAdd(&agw[4 * 72 + dl], 1.0f);
  }
  __syncthreads();

  if (tid < 64) {
    const int n = tid;
    const float a0 = aggT[0][0][n] + aggT[1][0][n] + aggT[2][0][n] + aggT[3][0][n];
    const float a1 = aggT[0][1][n] + aggT[1][1][n] + aggT[2][1][n] + aggT[3][1][n];
    const float a2 = aggT[0][2][n] + aggT[1][2][n] + aggT[2][2][n] + aggT[3][2][n];
    const float a3v = aggT[0][3][n] + aggT[1][3][n] + aggT[2][3][n] + aggT[3][3][n];
    const float dg = aggT[0][4][n] + aggT[1][4][n] + aggT[2][4][n] + aggT[3][4][n];
    *(float4*)&aggC[n][0] = make_float4(a0, a1, a2, a3v);
    aggC[n][4] = dg;
  }
  __syncthreads();

  const int c = tid & 63, qq = tid >> 6;
  const float wc0 = w2s[c], wc1 = w2s[64 + c], wc2 = w2s[128 + c], wc3 = w2s[192 + c];
  const float b2c = b2s[c];
  float s = 0.f, ss = 0.f;
  for (int n = qq; n < 64; n += 4) {
    const float4 a = *(const float4*)&aggC[n][0];
    const float dg = aggC[n][4];
    float v = a.x * wc0 + a.y * wc1 + a.z * wc2 + a.w * wc3 + dg * b2c;
    out0[(size_t)(((b << 6) + n) << 6) + c] = f2bf(v);
    s += v; ss += v * v;
  }
  rs[qq][c] = s; rss[qq][c] = ss;
  __syncthreads();
  if (tid < 64) {
    float* dst = stats1 + ((b & (REP - 1)) << 7);
    atomicAdd(&dst[tid], rs[0][tid] + rs[1][tid] + rs[2][tid] + rs[3][tid]);
    atomicAdd(&dst[64 + tid], rss[0][tid] + rss[1][tid] + rss[2][tid] + rss[3][tid]);
  }
}

// ---------------------------------------------------------------------------
// k_convm: bf16 in [l][c] -> BN(replica-sum stats)+ReLU -> Yt bf16 -> conv1d
// as MFMA GEMM (M=o, N=l, K=192) -> bf16 out [l][o] + fp32 replica stats.
// ---------------------------------------------------------------------------
__global__ __launch_bounds__(256) void k_convm(
    const ushort* __restrict__ in,           // [1024][64 l][64 c] bf16
    const float* __restrict__ stats_in,      // [REP][128]
    const float* __restrict__ gamma, const float* __restrict__ beta,
    const ushort* __restrict__ cwt, const float* __restrict__ cb,
    ushort* __restrict__ out,                // [1024][64 l][64 o] bf16
    float* __restrict__ stats_out)           // [REP][128]
{
  __shared__ ushort As[64][200];
  __shared__ ushort Yt[66][72];
  __shared__ float aco[64], bco[64], cbs[64];
  __shared__ float ldsS[64], ldsSS[64];
  const int tid = threadIdx.x;
  const int b = blockIdx.x;

  if (tid < 64) {
    float sm = 0.f, sq = 0.f;
#pragma unroll 8
    for (int r = 0; r < REP; ++r) {
      sm += stats_in[(r << 7) + tid];
      sq += stats_in[(r << 7) + 64 + tid];
    }
    const float mean = sm * (1.0f / CNTF);
    const float var = sq * (1.0f / CNTF) - mean * mean;
    const float a = gamma[tid] * rsqrtf(var + EPSV);
    aco[tid] = a;
    bco[tid] = beta[tid] - mean * a;
    cbs[tid] = cb[tid];
    Yt[0][tid] = 0;
    Yt[65][tid] = 0;
  }
  __syncthreads();

  const size_t base = (size_t)b << 12;
  {
    const int lr = tid >> 2, p = (tid & 3) << 4;
    const ushort8 r0 = *(const ushort8*)&in[base + (lr << 6) + p];
    const ushort8 r1 = *(const ushort8*)&in[base + (lr << 6) + p + 8];
    ushort tmp[16];
#pragma unroll
    for (int j = 0; j < 8; ++j)
      tmp[j] = f2bf(fmaxf(fmaf(aco[p + j], bf2f(r0[j]), bco[p + j]), 0.f));
#pragma unroll
    for (int j = 0; j < 8; ++j)
      tmp[8 + j] = f2bf(fmaxf(fmaf(aco[p + 8 + j], bf2f(r1[j]), bco[p + 8 + j]), 0.f));
    *(ushort8*)&Yt[lr + 1][p] = *(ushort8*)&tmp[0];
    *(ushort8*)&Yt[lr + 1][p + 8] = *(ushort8*)&tmp[8];
  }
  {
    const ushort8* gw = (const ushort8*)cwt;
#pragma unroll
    for (int i = 0; i < 6; ++i) {
      const int e8 = (i << 8) + tid;
      const int o = e8 / 24, k8 = (e8 - o * 24) << 3;
      *(ushort8*)&As[o][k8] = gw[e8];
    }
  }
  __syncthreads();

  const int lane = tid & 63, w = tid >> 6;
  const int lm = lane & 15, q = lane >> 4;
  f32x4 acc[4];
#pragma unroll
  for (int nt = 0; nt < 4; ++nt) acc[nt] = (f32x4){0.f, 0.f, 0.f, 0.f};

#pragma unroll
  for (int kk = 0; kk < 3; ++kk) {
#pragma unroll
    for (int ks = 0; ks < 2; ++ks) {
      const short8 af = *(const short8*)&As[(w << 4) + lm][(kk << 6) + (ks << 5) + (q << 3)];
#pragma unroll
      for (int nt = 0; nt < 4; ++nt) {
        const short8 bfr = *(const short8*)&Yt[(nt << 4) + lm + kk][(ks << 5) + (q << 3)];
        acc[nt] = __builtin_amdgcn_mfma_f32_16x16x32_bf16(af, bfr, acc[nt], 0, 0, 0);
      }
    }
  }

  const int obase = (w << 4) + (q << 2);
  const float4 cb4 = *(const float4*)&cbs[obase];
  float s[4] = {0.f, 0.f, 0.f, 0.f}, ss[4] = {0.f, 0.f, 0.f, 0.f};
#pragma unroll
  for (int nt = 0; nt < 4; ++nt) {
    const int l = (nt << 4) + lm;
    float4 v = make_float4(acc[nt][0] + cb4.x, acc[nt][1] + cb4.y,
                           acc[nt][2] + cb4.z, acc[nt][3] + cb4.w);
    *(ushort4*)&out[base + (l << 6) + obase] =
        make_ushort4(f2bf(v.x), f2bf(v.y), f2bf(v.z), f2bf(v.w));
    s[0] += v.x; ss[0] += v.x * v.x;
    s[1] += v.y; ss[1] += v.y * v.y;
    s[2] += v.z; ss[2] += v.z * v.z;
    s[3] += v.w; ss[3] += v.w * v.w;
  }
#pragma unroll
  for (int i = 0; i < 4; ++i) {
#pragma unroll
    for (int off = 1; off < 16; off <<= 1) {
      s[i] += __shfl_xor(s[i], off);
      ss[i] += __shfl_xor(ss[i], off);
    }
    if (lm == 0) { ldsS[obase + i] = s[i]; ldsSS[obase + i] = ss[i]; }
  }
  __syncthreads();
  if (tid < 64) {
    float* dst = stats_out + ((b & (REP - 1)) << 7);
    atomicAdd(&dst[tid], ldsS[tid]);
    atomicAdd(&dst[64 + tid], ldsSS[tid]);
  }
}

// ---------------------------------------------------------------------------
// k_mlp1: h1part[bz] = (BN3+ReLU(z3)) @ wm1 partial, bf16 MFMA 16x16x32.
// z3 bf16 [g][l][c]; wm1 pre-transposed chunk-major (no in-kernel transpose).
// Grid (16 Mtiles, 2 Ntiles of 128, 8 Ksplits). acc[8] per wave.
// ---------------------------------------------------------------------------
__global__ __launch_bounds__(256) void k_mlp1(
    const ushort* __restrict__ z3, const float* __restrict__ stats3,
    const float* __restrict__ g3, const float* __restrict__ be3,
    const ushort* __restrict__ wbf1t, float* __restrict__ h1part)
{
  __shared__ ushort Ys[64][72];
  __shared__ ushort Ws[128][72];
  __shared__ float a3s[64], b3s[64];
  const int tid = threadIdx.x;
  const int bx = blockIdx.x, by = blockIdx.y, bz = blockIdx.z;

  if (tid < 64) {
    float sm = 0.f, sq = 0.f;
#pragma unroll 8
    for (int r = 0; r < REP; ++r) {
      sm += stats3[(r << 7) + tid];
      sq += stats3[(r << 7) + 64 + tid];
    }
    const float mean = sm * (1.0f / CNTF);
    const float var = sq * (1.0f / CNTF) - mean * mean;
    const float a = g3[tid] * rsqrtf(var + EPSV);
    a3s[tid] = a;
    b3s[tid] = be3[tid] - mean * a;
  }
  __syncthreads();

  const int lane = tid & 63, w = tid >> 6;
  const int lm = lane & 15, q = lane >> 4;
  const int gy = tid >> 2, py = (tid & 3) << 4;   // Ys staging: graph, k-part
  const int nn = tid >> 1, pp = (tid & 1) << 2;   // Ws staging: n-row, short8-part
  const int g0 = bx << 6, n0 = by << 7;

  f32x4 acc[8];
#pragma unroll
  for (int nt = 0; nt < 8; ++nt) acc[nt] = (f32x4){0.f, 0.f, 0.f, 0.f};

  const size_t ybase = ((size_t)(g0 + gy) << 12);

#pragma unroll 1
  for (int ck = 0; ck < 8; ++ck) {
    const int kc = (bz << 9) + (ck << 6);
    if (ck) __syncthreads();
    // --- stage Ys: BN3+ReLU on bf16 z3 (channel = within-chunk index)
    {
      const ushort* src = z3 + ybase + kc + py;
      const ushort8 r0 = *(const ushort8*)src;
      const ushort8 r1 = *(const ushort8*)(src + 8);
      ushort tmp[16];
#pragma unroll
      for (int j = 0; j < 8; ++j)
        tmp[j] = f2bf(fmaxf(fmaf(a3s[py + j], bf2f(r0[j]), b3s[py + j]), 0.f));
#pragma unroll
      for (int j = 0; j < 8; ++j)
        tmp[8 + j] = f2bf(fmaxf(fmaf(a3s[py + 8 + j], bf2f(r1[j]), b3s[py + 8 + j]), 0.f));
      *(ushort8*)&Ys[gy][py] = *(ushort8*)&tmp[0];
      *(ushort8*)&Ys[gy][py + 8] = *(ushort8*)&tmp[8];
    }
    // --- stage Ws: straight copies from chunk-major wbf1t
    {
      const ushort8* gw = (const ushort8*)(wbf1t + ((size_t)((bz << 3) + ck) << 14) + (n0 << 6));
#pragma unroll
      for (int i = 0; i < 4; ++i)
        *(ushort8*)&Ws[nn][(pp + i) << 3] = gw[(nn << 3) + pp + i];
    }
    __syncthreads();
#pragma unroll
    for (int ks = 0; ks < 2; ++ks) {
      const short8 af = *(const short8*)&Ys[(w << 4) + lm][(ks << 5) + (q << 3)];
#pragma unroll
      for (int nt = 0; nt < 8; ++nt) {
        const short8 bfr = *(const short8*)&Ws[(nt << 4) + lm][(ks << 5) + (q << 3)];
        acc[nt] = __builtin_amdgcn_mfma_f32_16x16x32_bf16(af, bfr, acc[nt], 0, 0, 0);
      }
    }
  }

  float* dst0 = h1part + ((size_t)bz << 18);
  const int gout = g0 + (w << 4) + (q << 2);
#pragma unroll
  for (int nt = 0; nt < 8; ++nt) {
    const int col = n0 + (nt << 4) + lm;
#pragma unroll
    for (int i = 0; i < 4; ++i)
      dst0[((size_t)(gout + i) << 8) + col] = acc[nt][i];
  }
}

// ---------------------------------------------------------------------------
// k_tail: h1 = relu(sum_bz h1part + bm1) -> h2 -> h3 -> logits -> logsoftmax.
// 64 blocks x 16 graphs. (unchanged)
// ---------------------------------------------------------------------------
__global__ __launch_bounds__(256) void k_tail(
    const float* __restrict__ h1part, const float* __restrict__ bm1,
    const ushort* __restrict__ wbf2t, const float* __restrict__ bm2,
    const ushort* __restrict__ wbf3t, const float* __restrict__ bm3,
    const ushort* __restrict__ wptbf, const float* __restrict__ bp,
    float* __restrict__ out)
{
  __shared__ ushort Ws[256][72];
  __shared__ ushort h1s[16][264];
  __shared__ ushort h2s[16][264];
  ushort* wpt = &Ws[0][0];
  const int tid = threadIdx.x;
  const int g0 = blockIdx.x << 4;
  const int lane = tid & 63, w = tid >> 6;
  const int lm = lane & 15, q = lane >> 4;
  const int gr = q << 2;

  {
    const int r = tid >> 4, c0 = (tid & 15) << 4;
    const float* srcb = h1part + ((size_t)(g0 + r) << 8) + c0;
#pragma unroll
    for (int i = 0; i < 4; ++i) {
      float4 vs = *(const float4*)(bm1 + c0 + (i << 2));
#pragma unroll
      for (int bz = 0; bz < 8; ++bz) {
        const float4 p = *(const float4*)(srcb + ((size_t)bz << 18) + (i << 2));
        vs.x += p.x; vs.y += p.y; vs.z += p.z; vs.w += p.w;
      }
      *(ushort4*)&h1s[r][c0 + (i << 2)] = make_ushort4(
          f2bf(fmaxf(vs.x, 0.f)), f2bf(fmaxf(vs.y, 0.f)),
          f2bf(fmaxf(vs.z, 0.f)), f2bf(fmaxf(vs.w, 0.f)));
    }
  }

  // ---- GEMM2
  f32x4 acc[4];
#pragma unroll
  for (int nt = 0; nt < 4; ++nt) acc[nt] = (f32x4){0.f, 0.f, 0.f, 0.f};
#pragma unroll 1
  for (int ck = 0; ck < 4; ++ck) {
    __syncthreads();
    {
      const ushort8* gw = (const ushort8*)(wbf2t + (ck << 14));
#pragma unroll
      for (int i = 0; i < 8; ++i) {
        const int e8 = (i << 8) + tid;
        const int n = e8 >> 3, kk = (e8 & 7) << 3;
        *(ushort8*)&Ws[n][kk] = gw[e8];
      }
    }
    __syncthreads();
#pragma unroll
    for (int ks = 0; ks < 2; ++ks) {
      const short8 af = *(const short8*)&h1s[lm][(ck << 6) + (ks << 5) + (q << 3)];
#pragma unroll
      for (int nt = 0; nt < 4; ++nt) {
        const short8 bfr = *(const short8*)&Ws[(w << 6) + (nt << 4) + lm][(ks << 5) + (q << 3)];
        acc[nt] = __builtin_amdgcn_mfma_f32_16x16x32_bf16(af, bfr, acc[nt], 0, 0, 0);
      }
    }
  }
#pragma unroll
  for (int nt = 0; nt < 4; ++nt) {
    const int col = (w << 6) + (nt << 4) + lm;
    const float bv = bm2[col];
#pragma unroll
    for (int i = 0; i < 4; ++i)
      h2s[gr + i][col] = f2bf(fmaxf(acc[nt][i] + bv, 0.f));
  }

  // ---- GEMM3
  f32x4 acc2[4];
#pragma unroll
  for (int nt = 0; nt < 4; ++nt) acc2[nt] = (f32x4){0.f, 0.f, 0.f, 0.f};
#pragma unroll 1
  for (int ck = 0; ck < 4; ++ck) {
    __syncthreads();
    {
      const ushort8* gw = (const ushort8*)(wbf3t + (ck << 14));
#pragma unroll
      for (int i = 0; i < 8; ++i) {
        const int e8 = (i << 8) + tid;
        const int n = e8 >> 3, kk = (e8 & 7) << 3;
        *(ushort8*)&Ws[n][kk] = gw[e8];
      }
    }
    __syncthreads();
#pragma unroll
    for (int ks = 0; ks < 2; ++ks) {
      const short8 af = *(const short8*)&h2s[lm][(ck << 6) + (ks << 5) + (q << 3)];
#pragma unroll
      for (int nt = 0; nt < 4; ++nt) {
        const short8 bfr = *(const short8*)&Ws[(w << 6) + (nt << 4) + lm][(ks << 5) + (q << 3)];
        acc2[nt] = __builtin_amdgcn_mfma_f32_16x16x32_bf16(af, bfr, acc2[nt], 0, 0, 0);
      }
    }
  }

  __syncthreads();
  {
    const ushort8* gw = (const ushort8*)wptbf;
#pragma unroll
    for (int i = 0; i < 2; ++i) {
      const int e8 = (i << 8) + tid;
      const int flat = e8 << 3;
      const int a = flat >> 8, kk = flat & 255;
      *(ushort8*)&wpt[a * 264 + kk] = gw[e8];
    }
  }
#pragma unroll
  for (int nt = 0; nt < 4; ++nt) {
    const int col = (w << 6) + (nt << 4) + lm;
    const float bv = bm3[col];
#pragma unroll
    for (int i = 0; i < 4; ++i)
      h2s[gr + i][col] = f2bf(fmaxf(acc2[nt][i] + bv, 0.f));
  }
  __syncthreads();

  if (w == 0) {
    f32x4 lacc = (f32x4){0.f, 0.f, 0.f, 0.f};
#pragma unroll
    for (int ks = 0; ks < 8; ++ks) {
      const short8 af = *(const short8*)&h2s[lm][(ks << 5) + (q << 3)];
      const short8 bfr = *(const short8*)&wpt[lm * 264 + (ks << 5) + (q << 3)];
      lacc = __builtin_amdgcn_mfma_f32_16x16x32_bf16(af, bfr, lacc, 0, 0, 0);
    }
    const float bpv = bp[lm];
    float lg[4], mx[4], se[4];
#pragma unroll
    for (int i = 0; i < 4; ++i) {
      lg[i] = lacc[i] + bpv;
      float m = lg[i];
#pragma unroll
      for (int off = 1; off < 16; off <<= 1) m = fmaxf(m, __shfl_xor(m, off));
      mx[i] = m;
      float e = expf(lg[i] - m);
#pragma unroll
      for (int off = 1; off < 16; off <<= 1) e += __shfl_xor(e, off);
      se[i] = e;
    }
#pragma unroll
    for (int i = 0; i < 4; ++i)
      out[((g0 + gr + i) << 4) + lm] = (lg[i] - mx[i]) - logf(se[i]);
  }
}

// ---------------------------------------------------------------------------
extern "C" void kernel_launch(void* const* d_in, const int* in_sizes, int n_in,
                              void* d_out, int out_size, void* d_ws, size_t ws_size,
                              hipStream_t stream)
{
  const float* x   = (const float*)d_in[0];
  const int*   ei  = (const int*)d_in[1];
  const float* w1  = (const float*)d_in[2];
  const float* b1  = (const float*)d_in[3];
  const float* w2  = (const float*)d_in[4];
  const float* b2  = (const float*)d_in[5];
  const float* c2w = (const float*)d_in[6];
  const float* c2b = (const float*)d_in[7];
  const float* c3w = (const float*)d_in[8];
  const float* c3b = (const float*)d_in[9];
  const float* g1  = (const float*)d_in[10];
  const float* be1 = (const float*)d_in[11];
  const float* g2  = (const float*)d_in[12];
  const float* be2 = (const float*)d_in[13];
  const float* g3  = (const float*)d_in[14];
  const float* be3 = (const float*)d_in[15];
  const float* wm1 = (const float*)d_in[16];
  const float* bm1 = (const float*)d_in[17];
  const float* wm2 = (const float*)d_in[18];
  const float* bm2 = (const float*)d_in[19];
  const float* wm3 = (const float*)d_in[20];
  const float* bm3 = (const float*)d_in[21];
  const float* wp  = (const float*)d_in[22];
  const float* bp  = (const float*)d_in[23];

  char* ws = (char*)d_ws;
  ushort* ubuf0 = (ushort*)ws;                          // 8 MiB: out0 -> z3 (bf16)
  ushort* ubuf1 = (ushort*)(ws + ((size_t)8 << 20));    // 8 MiB: z2 (bf16)
  float*  h1part = (float*)(ws + ((size_t)16 << 20));   // 8 MiB fp32 partials
  ushort* wbf1t = (ushort*)(ws + ((size_t)24 << 20));   // 2 MiB bf16 wm1^T
  ushort* wbf2t = (ushort*)(ws + ((size_t)26 << 20));               // 128 KiB
  ushort* wbf3t = (ushort*)(ws + ((size_t)26 << 20) + (128 << 10)); // 128 KiB
  ushort* wptbf = (ushort*)(ws + ((size_t)26 << 20) + (256 << 10)); // 8 KiB
  float* stats = (float*)(ws + ((size_t)27 << 20));
  float* stats1 = stats;                  // [REP][128]
  float* stats2 = stats + REP * 128;
  float* stats3 = stats + 2 * REP * 128;
  ushort* cwt2 = (ushort*)d_out;          // d_out scratch, overwritten by k_tail
  ushort* cwt3 = (ushort*)d_out + 12288;

  k_prepw<<<dim3(418), dim3(256), 0, stream>>>(
      wm1, wm2, wm3, wp, c2w, c3w,
      wbf1t, wbf2t, wbf3t, wptbf, cwt2, cwt3, stats);
  k_edge<<<dim3(NB), dim3(256), 0, stream>>>(x, ei, w1, b1, w2, b2, ubuf0, stats1);
  k_convm<<<dim3(NB), dim3(256), 0, stream>>>(ubuf0, stats1, g1, be1, cwt2, c2b, ubuf1, stats2);
  k_convm<<<dim3(NB), dim3(256), 0, stream>>>(ubuf1, stats2, g2, be2, cwt3, c3b, ubuf0, stats3);
  k_mlp1<<<dim3(16, 2, 8), dim3(256), 0, stream>>>(ubuf0, stats3, g3, be3, wbf1t, h1part);
  k_tail<<<dim3(64), dim3(256), 0, stream>>>(h1part, bm1, wbf2t, bm2, wbf3t, bm3,
                                             wptbf, bp, (float*)d_out);
}